// Round 6
// baseline (6431.354 us; speedup 1.0000x reference)
//
#include <hip/hip_runtime.h>

#define BSZ 256
#define NND 22
#define BN_EPS 1e-5f

// ---------------------------------------------------------------------------
// Shared conv core: each thread computes R consecutive conv1d(k=7,pad=3)
// outputs (positions t0+R*tid ..) from LDS-staged input and LDS-staged
// weights (layout [c][k][o], float4-broadcast reads). R in {2,4}.
// s_in[c][i] = x[t0 + i - 3] (zero-padded OOB), SROW = R*NTH+8 (16B aligned).
// R=4 -> 64 accumulators max is too many at COUT=16 (VGPR spill, R4 lesson):
// use R=2 for COUT=16 kernels (32 accumulators).
// ---------------------------------------------------------------------------
template<int CIN, int COUT, int R, int SROW>
__device__ __forceinline__ void conv_coreR(
    const float (*s_in)[SROW], const float* s_w, int tid, float y[COUT][R]) {
#pragma unroll
  for (int o = 0; o < COUT; o++)
#pragma unroll
    for (int r = 0; r < R; r++) y[o][r] = 0.f;
#pragma unroll
  for (int c = 0; c < CIN; c++) {
    float xr[R + 6];
    if constexpr (R == 4) {
      const float4* xp = (const float4*)&s_in[c][4 * tid];  // 16B aligned
      float4 xa = xp[0], xb = xp[1];
      xr[0] = xa.x; xr[1] = xa.y; xr[2] = xa.z; xr[3] = xa.w;
      xr[4] = xb.x; xr[5] = xb.y; xr[6] = xb.z; xr[7] = xb.w;
      xr[8] = s_in[c][4 * tid + 8]; xr[9] = s_in[c][4 * tid + 9];
    } else {
      const float2* xp = (const float2*)&s_in[c][2 * tid];  // 8B aligned
      float2 x0 = xp[0], x1 = xp[1], x2 = xp[2], x3 = xp[3];
      xr[0] = x0.x; xr[1] = x0.y; xr[2] = x1.x; xr[3] = x1.y;
      xr[4] = x2.x; xr[5] = x2.y; xr[6] = x3.x; xr[7] = x3.y;
    }
#pragma unroll
    for (int k = 0; k < 7; k++) {
      const float4* wp = (const float4*)&s_w[(c * 7 + k) * COUT];
#pragma unroll
      for (int o4 = 0; o4 < COUT / 4; o4++) {
        float4 wv = wp[o4];
#pragma unroll
        for (int r = 0; r < R; r++) {
          y[4 * o4 + 0][r] += wv.x * xr[r + k];
          y[4 * o4 + 1][r] += wv.y * xr[r + k];
          y[4 * o4 + 2][r] += wv.z * xr[r + k];
          y[4 * o4 + 3][r] += wv.w * xr[r + k];
        }
      }
    }
  }
}

template<int CIN, int COUT, int NTH>
__device__ __forceinline__ void stage_weights(const float* __restrict__ w,
                                              float* s_w, int tid) {
  for (int i = tid; i < CIN * 7 * COUT; i += NTH) {
    int c = i / (7 * COUT), k = (i / COUT) % 7, o = i % COUT;
    s_w[i] = w[(o * CIN + c) * 7 + k];
  }
}

// ---------------------------------------------------------------------------
// Stats pass: conv + per-channel sum/sum^2 over tile -> private partial slot.
// grid: (NT, B, N), block NTH. TILE = R*NTH conv positions.
// part slot = ((n*NT + tile)*BSZ + b), 2*COUT floats.
// ---------------------------------------------------------------------------
template<int CIN, int COUT, int LIN, int NTH, int NT, int R>
__global__ __launch_bounds__(NTH) void conv_statsR(
    const float* __restrict__ in, long sn, long sb, long sc,
    const float* __restrict__ w, float* __restrict__ part) {
  const int TILE = R * NTH;
  const int SROW = TILE + 8;
  __shared__ alignas(16) float s_in[CIN][SROW];
  __shared__ alignas(16) float s_w[CIN * 7 * COUT];
  __shared__ float s_red[2][NTH / 64][COUT];
  int tid = threadIdx.x, n = blockIdx.z, b = blockIdx.y;
  int t0 = blockIdx.x * TILE;
  const float* base = in + (long)n * sn + (long)b * sb;
  stage_weights<CIN, COUT, NTH>(w, s_w, tid);
  for (int c = 0; c < CIN; c++)
    for (int i = tid; i < TILE + 6; i += NTH) {
      int l = t0 + i - 3;
      s_in[c][i] = (l >= 0 && l < LIN) ? base[(long)c * sc + l] : 0.f;
    }
  __syncthreads();
  float y[COUT][R];
  conv_coreR<CIN, COUT, R, SROW>(s_in, s_w, tid, y);
  bool valid = (t0 + R * tid) < LIN;  // LIN % R == 0: all-or-nothing
  int lane = tid & 63, wv = tid >> 6;
#pragma unroll
  for (int o = 0; o < COUT; o++) {
    float s = 0.f, q = 0.f;
    if (valid) {
#pragma unroll
      for (int r = 0; r < R; r++) { s += y[o][r]; q += y[o][r] * y[o][r]; }
    }
#pragma unroll
    for (int off = 32; off > 0; off >>= 1) {
      s += __shfl_down(s, off, 64);
      q += __shfl_down(q, off, 64);
    }
    if (lane == 0) { s_red[0][wv][o] = s; s_red[1][wv][o] = q; }
  }
  __syncthreads();
  if (tid < COUT) {
    float s = 0.f, q = 0.f;
#pragma unroll
    for (int g = 0; g < NTH / 64; g++) { s += s_red[0][g][tid]; q += s_red[1][g][tid]; }
    long slot = ((long)n * NT + blockIdx.x) * BSZ + b;
    part[slot * (2 * COUT) + tid] = s;
    part[slot * (2 * COUT) + COUT + tid] = q;
  }
}

// ---------------------------------------------------------------------------
// Reduce partials -> BN scale/shift per (node, channel).
// scs layout: scs[n*64 + o] = scale, scs[n*64 + 32 + o] = shift
// ---------------------------------------------------------------------------
template<int C, int NSLOT, int LIN>
__global__ __launch_bounds__(256) void stats_reduce(
    const float* __restrict__ part,
    const float* __restrict__ gamma, const float* __restrict__ beta,
    float* __restrict__ scs) {
  const int V = 2 * C;
  const int GRP = 256 / V;
  int n = blockIdx.x, tid = threadIdx.x;
  int j = tid % V, g = tid / V;
  const float* p = part + (long)n * NSLOT * V;
  float s = 0.f;
  for (int sl = g; sl < NSLOT; sl += GRP) s += p[(long)sl * V + j];
  __shared__ float red[V][GRP];
  __shared__ float tot[V];
  red[j][g] = s;
  __syncthreads();
  if (tid < V) {
    float t = 0.f;
#pragma unroll
    for (int gg = 0; gg < GRP; gg++) t += red[tid][gg];
    tot[tid] = t;
  }
  __syncthreads();
  if (tid < C) {
    float cnt = (float)BSZ * (float)LIN;
    float m = tot[tid] / cnt;
    float var = tot[C + tid] / cnt - m * m;
    float istd = 1.0f / sqrtf(var + BN_EPS);
    float scl = gamma[tid] * istd;
    scs[n * 64 + tid] = scl;
    scs[n * 64 + 32 + tid] = beta[tid] - m * scl;
  }
}

// ---------------------------------------------------------------------------
// Apply pass (R=4): conv + BN + ReLU + MaxPool(2) -> 2 pooled, float2 store.
// grid: (NT, B, N), block NTH. outh layout [n][b][COUT][LP]
// ---------------------------------------------------------------------------
template<int CIN, int COUT, int LIN, int NTH>
__global__ __launch_bounds__(NTH) void conv_bn_pool4(
    const float* __restrict__ in, long sn, long sb, long sc,
    const float* __restrict__ w, const float* __restrict__ scs,
    float* __restrict__ outh) {
  const int LP = LIN / 2;
  const int TILE = 4 * NTH;
  const int SROW = TILE + 8;
  __shared__ alignas(16) float s_in[CIN][SROW];
  __shared__ alignas(16) float s_w[CIN * 7 * COUT];
  __shared__ float s_scale[COUT], s_shift[COUT];
  int tid = threadIdx.x, n = blockIdx.z, b = blockIdx.y;
  int P0 = blockIdx.x * (2 * NTH);
  int t0 = 2 * P0;
  const float* base = in + (long)n * sn + (long)b * sb;
  if (tid < COUT) {
    s_scale[tid] = scs[n * 64 + tid];
    s_shift[tid] = scs[n * 64 + 32 + tid];
  }
  stage_weights<CIN, COUT, NTH>(w, s_w, tid);
  for (int c = 0; c < CIN; c++)
    for (int i = tid; i < TILE + 6; i += NTH) {
      int l = t0 + i - 3;
      s_in[c][i] = (l >= 0 && l < LIN) ? base[(long)c * sc + l] : 0.f;
    }
  __syncthreads();
  float y[COUT][4];
  conv_coreR<CIN, COUT, 4, SROW>(s_in, s_w, tid, y);
  int pl = P0 + 2 * tid;
  if (pl >= LP) return;  // LP % 2 == 0: all-or-nothing
  long obase = ((long)n * BSZ + b) * COUT * (long)LP;
#pragma unroll
  for (int o = 0; o < COUT; o++) {
    float a0 = y[o][0] * s_scale[o] + s_shift[o];
    float a1 = y[o][1] * s_scale[o] + s_shift[o];
    float a2 = y[o][2] * s_scale[o] + s_shift[o];
    float a3 = y[o][3] * s_scale[o] + s_shift[o];
    float2 v;
    v.x = fmaxf(fmaxf(a0, a1), 0.f);
    v.y = fmaxf(fmaxf(a2, a3), 0.f);
    *(float2*)&outh[obase + (long)o * LP + pl] = v;
  }
}

// ---------------------------------------------------------------------------
// Block-3 apply (R=2) fused with AdaptiveAvgPool(1) -> feat[b][n][16].
// grid: (1, B, N), block 256; thread covers conv positions 2*tid, 2*tid+1
// -> one pooled value; valid iff tid < LP.
// ---------------------------------------------------------------------------
template<int CIN, int COUT, int LIN, int NTH>
__global__ __launch_bounds__(NTH) void conv_bn_pool_feat2(
    const float* __restrict__ in, long sn, long sb, long sc,
    const float* __restrict__ w, const float* __restrict__ scs,
    float* __restrict__ feat) {
  const int LP = LIN / 2;
  const int TILE = 2 * NTH;
  const int SROW = TILE + 8;
  __shared__ alignas(16) float s_in[CIN][SROW];
  __shared__ alignas(16) float s_w[CIN * 7 * COUT];
  __shared__ float s_scale[COUT], s_shift[COUT];
  __shared__ float s_red[NTH / 64][COUT];
  int tid = threadIdx.x, n = blockIdx.z, b = blockIdx.y;
  const float* base = in + (long)n * sn + (long)b * sb;
  if (tid < COUT) {
    s_scale[tid] = scs[n * 64 + tid];
    s_shift[tid] = scs[n * 64 + 32 + tid];
  }
  stage_weights<CIN, COUT, NTH>(w, s_w, tid);
  for (int c = 0; c < CIN; c++)
    for (int i = tid; i < TILE + 6; i += NTH) {
      int l = i - 3;
      s_in[c][i] = (l >= 0 && l < LIN) ? base[(long)c * sc + l] : 0.f;
    }
  __syncthreads();
  float y[COUT][2];
  conv_coreR<CIN, COUT, 2, SROW>(s_in, s_w, tid, y);
  bool valid = tid < LP;
  int lane = tid & 63, wv = tid >> 6;
#pragma unroll
  for (int o = 0; o < COUT; o++) {
    float s = 0.f;
    if (valid) {
      float a0 = y[o][0] * s_scale[o] + s_shift[o];
      float a1 = y[o][1] * s_scale[o] + s_shift[o];
      s = fmaxf(fmaxf(a0, a1), 0.f);
    }
#pragma unroll
    for (int off = 32; off > 0; off >>= 1) s += __shfl_down(s, off, 64);
    if (lane == 0) s_red[wv][o] = s;
  }
  __syncthreads();
  if (tid < COUT) {
    float s = 0.f;
#pragma unroll
    for (int g = 0; g < NTH / 64; g++) s += s_red[g][tid];
    feat[((long)b * NND + n) * COUT + tid] = s * (1.0f / (float)LP);
  }
}

// ---------------------------------------------------------------------------
// Graph tail: adjacency (top-4 incl self) + 3 GCN layers + node-mean + MLP head
// grid: (B), block: 256. One workgroup per batch element, all in LDS.
// ---------------------------------------------------------------------------
__global__ __launch_bounds__(256) void graph_head(
    const float* __restrict__ feat,
    const float* __restrict__ gw1, const float* __restrict__ gb1,
    const float* __restrict__ gw2, const float* __restrict__ gb2,
    const float* __restrict__ gw3, const float* __restrict__ gb3,
    const float* __restrict__ fw1, const float* __restrict__ fb1,
    const float* __restrict__ fw2, const float* __restrict__ fb2,
    float* __restrict__ out) {
  int b = blockIdx.x, tid = threadIdx.x;
  __shared__ float s_feat[NND][16];
  __shared__ float s_sq[NND];
  __shared__ float s_dist[NND][NND];
  __shared__ float s_adj[NND][NND];
  __shared__ float s_x[NND][128];
  __shared__ float s_t[NND][128];
  __shared__ float s_pool[128];
  __shared__ float s_h[64];
  for (int i = tid; i < NND * 16; i += 256) s_feat[i >> 4][i & 15] = feat[b * NND * 16 + i];
  __syncthreads();
  if (tid < NND) {
    float s = 0.f;
    for (int c = 0; c < 16; c++) s += s_feat[tid][c] * s_feat[tid][c];
    s_sq[tid] = s;
  }
  __syncthreads();
  for (int i = tid; i < NND * NND; i += 256) {
    int nn = i / NND, m = i % NND;
    float d = 0.f;
    for (int c = 0; c < 16; c++) d += s_feat[nn][c] * s_feat[m][c];
    s_dist[nn][m] = s_sq[nn] + s_sq[m] - 2.f * d;  // diagonal exactly 0
    s_adj[nn][m] = 0.f;
  }
  __syncthreads();
  if (tid < NND) {  // top-4 smallest per row, ties -> earliest index (matches top_k)
    unsigned used = 0;
    for (int j = 0; j < 4; j++) {
      float best = 3.4e38f; int bi = 0;
      for (int m = 0; m < NND; m++)
        if (!((used >> m) & 1u) && s_dist[tid][m] < best) { best = s_dist[tid][m]; bi = m; }
      used |= 1u << bi;
      s_adj[tid][bi] = 0.25f;
    }
  }
  __syncthreads();
  // ---- GCN layer 1: 16 -> 32 ----
  for (int i = tid; i < NND * 32; i += 256) {
    int nn = i / 32, f = i % 32;
    float a = 0.f;
    for (int c = 0; c < 16; c++) a += s_feat[nn][c] * gw1[c * 32 + f];
    s_t[nn][f] = a;
  }
  __syncthreads();
  for (int i = tid; i < NND * 32; i += 256) {
    int nn = i / 32, f = i % 32;
    float a = gb1[f];
    for (int m = 0; m < NND; m++) a += s_adj[nn][m] * s_t[m][f];
    s_x[nn][f] = fmaxf(a, 0.f);
  }
  __syncthreads();
  // ---- GCN layer 2: 32 -> 64 ----
  for (int i = tid; i < NND * 64; i += 256) {
    int nn = i / 64, f = i % 64;
    float a = 0.f;
    for (int c = 0; c < 32; c++) a += s_x[nn][c] * gw2[c * 64 + f];
    s_t[nn][f] = a;
  }
  __syncthreads();
  for (int i = tid; i < NND * 64; i += 256) {
    int nn = i / 64, f = i % 64;
    float a = gb2[f];
    for (int m = 0; m < NND; m++) a += s_adj[nn][m] * s_t[m][f];
    s_x[nn][f] = fmaxf(a, 0.f);
  }
  __syncthreads();
  // ---- GCN layer 3: 64 -> 128 ----
  for (int i = tid; i < NND * 128; i += 256) {
    int nn = i / 128, f = i % 128;
    float a = 0.f;
    for (int c = 0; c < 64; c++) a += s_x[nn][c] * gw3[c * 128 + f];
    s_t[nn][f] = a;
  }
  __syncthreads();
  for (int i = tid; i < NND * 128; i += 256) {
    int nn = i / 128, f = i % 128;
    float a = gb3[f];
    for (int m = 0; m < NND; m++) a += s_adj[nn][m] * s_t[m][f];
    s_x[nn][f] = fmaxf(a, 0.f);
  }
  __syncthreads();
  if (tid < 128) {
    float a = 0.f;
    for (int m = 0; m < NND; m++) a += s_x[m][tid];
    s_pool[tid] = a * (1.0f / (float)NND);
  }
  __syncthreads();
  if (tid < 64) {
    float a = fb1[tid];
    for (int c = 0; c < 128; c++) a += s_pool[c] * fw1[c * 64 + tid];
    s_h[tid] = a;
  }
  __syncthreads();
  if (tid < 4) {
    float a = fb2[tid];
    for (int c = 0; c < 64; c++) a += s_h[c] * fw2[c * 4 + tid];
    out[b * 4 + tid] = a;
  }
}

extern "C" void kernel_launch(void* const* d_in, const int* in_sizes, int n_in,
                              void* d_out, int out_size, void* d_ws, size_t ws_size,
                              hipStream_t stream) {
  (void)in_sizes; (void)n_in; (void)out_size; (void)ws_size;
  const float* x   = (const float*)d_in[0];
  const float* w1  = (const float*)d_in[1];
  const float* g1  = (const float*)d_in[2];
  const float* b1  = (const float*)d_in[3];
  const float* w2  = (const float*)d_in[4];
  const float* g2  = (const float*)d_in[5];
  const float* b2  = (const float*)d_in[6];
  const float* w3  = (const float*)d_in[7];
  const float* g3  = (const float*)d_in[8];
  const float* b3  = (const float*)d_in[9];
  const float* gw1 = (const float*)d_in[10];
  const float* gb1 = (const float*)d_in[11];
  const float* gw2 = (const float*)d_in[12];
  const float* gb2 = (const float*)d_in[13];
  const float* gw3 = (const float*)d_in[14];
  const float* gb3 = (const float*)d_in[15];
  const float* fw1 = (const float*)d_in[16];
  const float* fb1 = (const float*)d_in[17];
  const float* fw2 = (const float*)d_in[18];
  const float* fb2 = (const float*)d_in[19];

  float* ws = (float*)d_ws;
  const long H1 = (long)NND * BSZ * 4 * 1000;  // 22,528,000 floats
  const long H2 = (long)NND * BSZ * 8 * 500;   // 22,528,000 floats
  float* h1   = ws;
  float* h2   = h1 + H1;
  float* feat = h2 + H2;                        // B*N*16 = 90,112
  float* scs1 = feat + (long)BSZ * NND * 16;    // scale/shift, 22*64 each
  float* scs2 = scs1 + NND * 64;
  float* scs3 = scs2 + NND * 64;
  float* p1   = scs3 + NND * 64;                // 22*512 slots * 8
  float* p2   = p1 + (long)NND * 512 * 8;       // 22*256 slots * 16
  float* p3   = p2 + (long)NND * 256 * 16;      // 22*256 slots * 32

  // block 1: input x is (B, N, T): node stride T, batch stride N*T
  conv_statsR<1, 4, 2000, 256, 2, 4><<<dim3(2, BSZ, NND), dim3(256), 0, stream>>>(
      x, 2000, (long)NND * 2000, 0, w1, p1);
  stats_reduce<4, 512, 2000><<<dim3(NND), dim3(256), 0, stream>>>(p1, g1, b1, scs1);
  conv_bn_pool4<1, 4, 2000, 256><<<dim3(2, BSZ, NND), dim3(256), 0, stream>>>(
      x, 2000, (long)NND * 2000, 0, w1, scs1, h1);
  // block 2: h1 layout [n][b][4][1000]
  conv_statsR<4, 8, 1000, 256, 1, 4><<<dim3(1, BSZ, NND), dim3(256), 0, stream>>>(
      h1, (long)BSZ * 4000, 4000, 1000, w2, p2);
  stats_reduce<8, 256, 1000><<<dim3(NND), dim3(256), 0, stream>>>(p2, g2, b2, scs2);
  conv_bn_pool4<4, 8, 1000, 256><<<dim3(1, BSZ, NND), dim3(256), 0, stream>>>(
      h1, (long)BSZ * 4000, 4000, 1000, w2, scs2, h2);
  // block 3: h2 layout [n][b][8][500]; R=2 to avoid VGPR spill at COUT=16
  conv_statsR<8, 16, 500, 256, 1, 2><<<dim3(1, BSZ, NND), dim3(256), 0, stream>>>(
      h2, (long)BSZ * 4000, 4000, 500, w3, p3);
  stats_reduce<16, 256, 500><<<dim3(NND), dim3(256), 0, stream>>>(p3, g3, b3, scs3);
  conv_bn_pool_feat2<8, 16, 500, 256><<<dim3(1, BSZ, NND), dim3(256), 0, stream>>>(
      h2, (long)BSZ * 4000, 4000, 500, w3, scs3, feat);
  // graph tail
  graph_head<<<dim3(BSZ), dim3(256), 0, stream>>>(
      feat, gw1, gb1, gw2, gb2, gw3, gb3, fw1, fb1, fw2, fb2, (float*)d_out);
}

// Round 7
// 540.544 us; speedup vs baseline: 11.8979x; 11.8979x over previous
//
#include <hip/hip_runtime.h>

#define BSZ 256
#define NND 22
#define BN_EPS 1e-5f

// ---------------------------------------------------------------------------
// Shared conv core (CIN<=4 only — full unroll is safe there; CIN=8 kernels
// are hand-written below with unroll-1 c-loop + channel split, after the
// R4/R5 lesson: fully-unrolled CIN=8 bodies spill to 256 VGPR + scratch).
// ---------------------------------------------------------------------------
template<int CIN, int COUT, int R, int SROW>
__device__ __forceinline__ void conv_coreR(
    const float (*s_in)[SROW], const float* s_w, int tid, float y[COUT][R]) {
#pragma unroll
  for (int o = 0; o < COUT; o++)
#pragma unroll
    for (int r = 0; r < R; r++) y[o][r] = 0.f;
#pragma unroll
  for (int c = 0; c < CIN; c++) {
    float xr[R + 6];
    if constexpr (R == 4) {
      const float4* xp = (const float4*)&s_in[c][4 * tid];  // 16B aligned
      float4 xa = xp[0], xb = xp[1];
      xr[0] = xa.x; xr[1] = xa.y; xr[2] = xa.z; xr[3] = xa.w;
      xr[4] = xb.x; xr[5] = xb.y; xr[6] = xb.z; xr[7] = xb.w;
      xr[8] = s_in[c][4 * tid + 8]; xr[9] = s_in[c][4 * tid + 9];
    } else {
      const float2* xp = (const float2*)&s_in[c][2 * tid];  // 8B aligned
      float2 x0 = xp[0], x1 = xp[1], x2 = xp[2], x3 = xp[3];
      xr[0] = x0.x; xr[1] = x0.y; xr[2] = x1.x; xr[3] = x1.y;
      xr[4] = x2.x; xr[5] = x2.y; xr[6] = x3.x; xr[7] = x3.y;
    }
#pragma unroll
    for (int k = 0; k < 7; k++) {
      const float4* wp = (const float4*)&s_w[(c * 7 + k) * COUT];
#pragma unroll
      for (int o4 = 0; o4 < COUT / 4; o4++) {
        float4 wv = wp[o4];
#pragma unroll
        for (int r = 0; r < R; r++) {
          y[4 * o4 + 0][r] += wv.x * xr[r + k];
          y[4 * o4 + 1][r] += wv.y * xr[r + k];
          y[4 * o4 + 2][r] += wv.z * xr[r + k];
          y[4 * o4 + 3][r] += wv.w * xr[r + k];
        }
      }
    }
  }
}

template<int CIN, int COUT, int NTH>
__device__ __forceinline__ void stage_weights(const float* __restrict__ w,
                                              float* s_w, int tid) {
  for (int i = tid; i < CIN * 7 * COUT; i += NTH) {
    int c = i / (7 * COUT), k = (i / COUT) % 7, o = i % COUT;
    s_w[i] = w[(o * CIN + c) * 7 + k];
  }
}

// ---------------------------------------------------------------------------
// Stats pass (CIN<=4): conv + per-channel sum/sum^2 -> private partial slot.
// grid: (NT, B, N), block NTH. TILE = R*NTH conv positions.
// ---------------------------------------------------------------------------
template<int CIN, int COUT, int LIN, int NTH, int NT, int R>
__global__ __launch_bounds__(NTH) void conv_statsR(
    const float* __restrict__ in, long sn, long sb, long sc,
    const float* __restrict__ w, float* __restrict__ part) {
  const int TILE = R * NTH;
  const int SROW = TILE + 8;
  __shared__ alignas(16) float s_in[CIN][SROW];
  __shared__ alignas(16) float s_w[CIN * 7 * COUT];
  __shared__ float s_red[2][NTH / 64][COUT];
  int tid = threadIdx.x, n = blockIdx.z, b = blockIdx.y;
  int t0 = blockIdx.x * TILE;
  const float* base = in + (long)n * sn + (long)b * sb;
  stage_weights<CIN, COUT, NTH>(w, s_w, tid);
  for (int c = 0; c < CIN; c++)
    for (int i = tid; i < TILE + 6; i += NTH) {
      int l = t0 + i - 3;
      s_in[c][i] = (l >= 0 && l < LIN) ? base[(long)c * sc + l] : 0.f;
    }
  __syncthreads();
  float y[COUT][R];
  conv_coreR<CIN, COUT, R, SROW>(s_in, s_w, tid, y);
  bool valid = (t0 + R * tid) < LIN;  // LIN % R == 0: all-or-nothing
  int lane = tid & 63, wv = tid >> 6;
#pragma unroll
  for (int o = 0; o < COUT; o++) {
    float s = 0.f, q = 0.f;
    if (valid) {
#pragma unroll
      for (int r = 0; r < R; r++) { s += y[o][r]; q += y[o][r] * y[o][r]; }
    }
#pragma unroll
    for (int off = 32; off > 0; off >>= 1) {
      s += __shfl_down(s, off, 64);
      q += __shfl_down(q, off, 64);
    }
    if (lane == 0) { s_red[0][wv][o] = s; s_red[1][wv][o] = q; }
  }
  __syncthreads();
  if (tid < COUT) {
    float s = 0.f, q = 0.f;
#pragma unroll
    for (int g = 0; g < NTH / 64; g++) { s += s_red[0][g][tid]; q += s_red[1][g][tid]; }
    long slot = ((long)n * NT + blockIdx.x) * BSZ + b;
    part[slot * (2 * COUT) + tid] = s;
    part[slot * (2 * COUT) + COUT + tid] = q;
  }
}

// ---------------------------------------------------------------------------
// Reduce partials -> BN scale/shift per (node, channel).
// scs layout: scs[n*64 + o] = scale, scs[n*64 + 32 + o] = shift
// ---------------------------------------------------------------------------
template<int C, int NSLOT, int LIN>
__global__ __launch_bounds__(256) void stats_reduce(
    const float* __restrict__ part,
    const float* __restrict__ gamma, const float* __restrict__ beta,
    float* __restrict__ scs) {
  const int V = 2 * C;
  const int GRP = 256 / V;
  int n = blockIdx.x, tid = threadIdx.x;
  int j = tid % V, g = tid / V;
  const float* p = part + (long)n * NSLOT * V;
  float s = 0.f;
  for (int sl = g; sl < NSLOT; sl += GRP) s += p[(long)sl * V + j];
  __shared__ float red[V][GRP];
  __shared__ float tot[V];
  red[j][g] = s;
  __syncthreads();
  if (tid < V) {
    float t = 0.f;
#pragma unroll
    for (int gg = 0; gg < GRP; gg++) t += red[tid][gg];
    tot[tid] = t;
  }
  __syncthreads();
  if (tid < C) {
    float cnt = (float)BSZ * (float)LIN;
    float m = tot[tid] / cnt;
    float var = tot[C + tid] / cnt - m * m;
    float istd = 1.0f / sqrtf(var + BN_EPS);
    float scl = gamma[tid] * istd;
    scs[n * 64 + tid] = scl;
    scs[n * 64 + 32 + tid] = beta[tid] - m * scl;
  }
}

// ---------------------------------------------------------------------------
// Apply pass (CIN<=4, R=4): conv + BN + ReLU + MaxPool(2), float2 store.
// grid: (NT, B, N), block NTH. outh layout [n][b][COUT][LP]
// ---------------------------------------------------------------------------
template<int CIN, int COUT, int LIN, int NTH>
__global__ __launch_bounds__(NTH) void conv_bn_pool4(
    const float* __restrict__ in, long sn, long sb, long sc,
    const float* __restrict__ w, const float* __restrict__ scs,
    float* __restrict__ outh) {
  const int LP = LIN / 2;
  const int TILE = 4 * NTH;
  const int SROW = TILE + 8;
  __shared__ alignas(16) float s_in[CIN][SROW];
  __shared__ alignas(16) float s_w[CIN * 7 * COUT];
  __shared__ float s_scale[COUT], s_shift[COUT];
  int tid = threadIdx.x, n = blockIdx.z, b = blockIdx.y;
  int P0 = blockIdx.x * (2 * NTH);
  int t0 = 2 * P0;
  const float* base = in + (long)n * sn + (long)b * sb;
  if (tid < COUT) {
    s_scale[tid] = scs[n * 64 + tid];
    s_shift[tid] = scs[n * 64 + 32 + tid];
  }
  stage_weights<CIN, COUT, NTH>(w, s_w, tid);
  for (int c = 0; c < CIN; c++)
    for (int i = tid; i < TILE + 6; i += NTH) {
      int l = t0 + i - 3;
      s_in[c][i] = (l >= 0 && l < LIN) ? base[(long)c * sc + l] : 0.f;
    }
  __syncthreads();
  float y[COUT][4];
  conv_coreR<CIN, COUT, 4, SROW>(s_in, s_w, tid, y);
  int pl = P0 + 2 * tid;
  if (pl >= LP) return;  // LP % 2 == 0: all-or-nothing
  long obase = ((long)n * BSZ + b) * COUT * (long)LP;
#pragma unroll
  for (int o = 0; o < COUT; o++) {
    float a0 = y[o][0] * s_scale[o] + s_shift[o];
    float a1 = y[o][1] * s_scale[o] + s_shift[o];
    float a2 = y[o][2] * s_scale[o] + s_shift[o];
    float a3 = y[o][3] * s_scale[o] + s_shift[o];
    float2 v;
    v.x = fmaxf(fmaxf(a0, a1), 0.f);
    v.y = fmaxf(fmaxf(a2, a3), 0.f);
    *(float2*)&outh[obase + (long)o * LP + pl] = v;
  }
}

// ---------------------------------------------------------------------------
// Block-3 stats (CIN=8, COUT=16): channel-split — 2 groups x 128 threads,
// group og handles channels og*8..og*8+7, 4 positions/thread (TILE=512>=500).
// c-loop NOT unrolled (unroll-1) to bound register pressure (R4/R5 lesson).
// grid: (1, B, N), block 256.
// ---------------------------------------------------------------------------
__global__ __launch_bounds__(256) void conv_stats3_split(
    const float* __restrict__ in, long sn, long sb, long sc,
    const float* __restrict__ w, float* __restrict__ part) {
  const int LIN = 500, SROW = 512 + 8;
  __shared__ alignas(16) float s_in[8][SROW];
  __shared__ alignas(16) float s_w[8 * 7 * 16];
  __shared__ float s_red[2][4][8];
  int tid = threadIdx.x, n = blockIdx.z, b = blockIdx.y;
  int og = tid >> 7, pt = tid & 127;
  const float* base = in + (long)n * sn + (long)b * sb;
  stage_weights<8, 16, 256>(w, s_w, tid);
  for (int c = 0; c < 8; c++)
    for (int i = tid; i < 512 + 6; i += 256) {
      int l = i - 3;
      s_in[c][i] = (l >= 0 && l < LIN) ? base[(long)c * sc + l] : 0.f;
    }
  __syncthreads();
  float y[8][4];
#pragma unroll
  for (int o = 0; o < 8; o++)
#pragma unroll
    for (int r = 0; r < 4; r++) y[o][r] = 0.f;
#pragma unroll 1
  for (int c = 0; c < 8; c++) {
    const float4* xp = (const float4*)&s_in[c][4 * pt];
    float4 xa = xp[0], xb = xp[1];
    float xr[10];
    xr[0] = xa.x; xr[1] = xa.y; xr[2] = xa.z; xr[3] = xa.w;
    xr[4] = xb.x; xr[5] = xb.y; xr[6] = xb.z; xr[7] = xb.w;
    xr[8] = s_in[c][4 * pt + 8]; xr[9] = s_in[c][4 * pt + 9];
#pragma unroll
    for (int k = 0; k < 7; k++) {
      float4 w0 = *(const float4*)&s_w[(c * 7 + k) * 16 + og * 8];
      float4 w1 = *(const float4*)&s_w[(c * 7 + k) * 16 + og * 8 + 4];
#pragma unroll
      for (int r = 0; r < 4; r++) {
        y[0][r] += w0.x * xr[r + k];
        y[1][r] += w0.y * xr[r + k];
        y[2][r] += w0.z * xr[r + k];
        y[3][r] += w0.w * xr[r + k];
        y[4][r] += w1.x * xr[r + k];
        y[5][r] += w1.y * xr[r + k];
        y[6][r] += w1.z * xr[r + k];
        y[7][r] += w1.w * xr[r + k];
      }
    }
  }
  bool valid = (4 * pt) < LIN;  // 500 % 4 == 0: all-or-nothing
  int lane = tid & 63, wv = tid >> 6;  // og is wave-uniform (waves 0,1 / 2,3)
#pragma unroll
  for (int o = 0; o < 8; o++) {
    float s = 0.f, q = 0.f;
    if (valid) {
#pragma unroll
      for (int r = 0; r < 4; r++) { s += y[o][r]; q += y[o][r] * y[o][r]; }
    }
#pragma unroll
    for (int off = 32; off > 0; off >>= 1) {
      s += __shfl_down(s, off, 64);
      q += __shfl_down(q, off, 64);
    }
    if (lane == 0) { s_red[0][wv][o] = s; s_red[1][wv][o] = q; }
  }
  __syncthreads();
  if (tid < 16) {  // channel ch = tid; group og2 = tid>>3 used waves 2*og2, 2*og2+1
    int og2 = tid >> 3, o = tid & 7;
    float s = s_red[0][2 * og2][o] + s_red[0][2 * og2 + 1][o];
    float q = s_red[1][2 * og2][o] + s_red[1][2 * og2 + 1][o];
    long slot = (long)n * BSZ + b;
    part[slot * 32 + tid] = s;
    part[slot * 32 + 16 + tid] = q;
  }
}

// ---------------------------------------------------------------------------
// Block-3 apply (CIN=8, COUT=16) fused with AdaptiveAvgPool -> feat[b][n][16].
// Same channel-split + unroll-1 structure. grid: (1, B, N), block 256.
// ---------------------------------------------------------------------------
__global__ __launch_bounds__(256) void conv_feat3_split(
    const float* __restrict__ in, long sn, long sb, long sc,
    const float* __restrict__ w, const float* __restrict__ scs,
    float* __restrict__ feat) {
  const int LIN = 500, LP = 250, SROW = 512 + 8;
  __shared__ alignas(16) float s_in[8][SROW];
  __shared__ alignas(16) float s_w[8 * 7 * 16];
  __shared__ float s_scale[16], s_shift[16];
  __shared__ float s_red[4][8];
  int tid = threadIdx.x, n = blockIdx.z, b = blockIdx.y;
  int og = tid >> 7, pt = tid & 127;
  const float* base = in + (long)n * sn + (long)b * sb;
  if (tid < 16) {
    s_scale[tid] = scs[n * 64 + tid];
    s_shift[tid] = scs[n * 64 + 32 + tid];
  }
  stage_weights<8, 16, 256>(w, s_w, tid);
  for (int c = 0; c < 8; c++)
    for (int i = tid; i < 512 + 6; i += 256) {
      int l = i - 3;
      s_in[c][i] = (l >= 0 && l < LIN) ? base[(long)c * sc + l] : 0.f;
    }
  __syncthreads();
  float y[8][4];
#pragma unroll
  for (int o = 0; o < 8; o++)
#pragma unroll
    for (int r = 0; r < 4; r++) y[o][r] = 0.f;
#pragma unroll 1
  for (int c = 0; c < 8; c++) {
    const float4* xp = (const float4*)&s_in[c][4 * pt];
    float4 xa = xp[0], xb = xp[1];
    float xr[10];
    xr[0] = xa.x; xr[1] = xa.y; xr[2] = xa.z; xr[3] = xa.w;
    xr[4] = xb.x; xr[5] = xb.y; xr[6] = xb.z; xr[7] = xb.w;
    xr[8] = s_in[c][4 * pt + 8]; xr[9] = s_in[c][4 * pt + 9];
#pragma unroll
    for (int k = 0; k < 7; k++) {
      float4 w0 = *(const float4*)&s_w[(c * 7 + k) * 16 + og * 8];
      float4 w1 = *(const float4*)&s_w[(c * 7 + k) * 16 + og * 8 + 4];
#pragma unroll
      for (int r = 0; r < 4; r++) {
        y[0][r] += w0.x * xr[r + k];
        y[1][r] += w0.y * xr[r + k];
        y[2][r] += w0.z * xr[r + k];
        y[3][r] += w0.w * xr[r + k];
        y[4][r] += w1.x * xr[r + k];
        y[5][r] += w1.y * xr[r + k];
        y[6][r] += w1.z * xr[r + k];
        y[7][r] += w1.w * xr[r + k];
      }
    }
  }
  bool valid = (2 * pt) < LP;  // thread covers pooled 2*pt, 2*pt+1
  int lane = tid & 63, wv = tid >> 6;
#pragma unroll
  for (int o = 0; o < 8; o++) {
    float s = 0.f;
    if (valid) {
      int ch = og * 8 + o;
      float a0 = y[o][0] * s_scale[ch] + s_shift[ch];
      float a1 = y[o][1] * s_scale[ch] + s_shift[ch];
      float a2 = y[o][2] * s_scale[ch] + s_shift[ch];
      float a3 = y[o][3] * s_scale[ch] + s_shift[ch];
      s = fmaxf(fmaxf(a0, a1), 0.f) + fmaxf(fmaxf(a2, a3), 0.f);
    }
#pragma unroll
    for (int off = 32; off > 0; off >>= 1) s += __shfl_down(s, off, 64);
    if (lane == 0) s_red[wv][o] = s;
  }
  __syncthreads();
  if (tid < 16) {
    int og2 = tid >> 3, o = tid & 7;
    float s = s_red[2 * og2][o] + s_red[2 * og2 + 1][o];
    feat[((long)b * NND + n) * 16 + tid] = s * (1.0f / (float)LP);
  }
}

// ---------------------------------------------------------------------------
// Graph tail: adjacency (top-4 incl self) + 3 GCN layers + node-mean + MLP head
// grid: (B), block: 256. One workgroup per batch element, all in LDS.
// ---------------------------------------------------------------------------
__global__ __launch_bounds__(256) void graph_head(
    const float* __restrict__ feat,
    const float* __restrict__ gw1, const float* __restrict__ gb1,
    const float* __restrict__ gw2, const float* __restrict__ gb2,
    const float* __restrict__ gw3, const float* __restrict__ gb3,
    const float* __restrict__ fw1, const float* __restrict__ fb1,
    const float* __restrict__ fw2, const float* __restrict__ fb2,
    float* __restrict__ out) {
  int b = blockIdx.x, tid = threadIdx.x;
  __shared__ float s_feat[NND][16];
  __shared__ float s_sq[NND];
  __shared__ float s_dist[NND][NND];
  __shared__ float s_adj[NND][NND];
  __shared__ float s_x[NND][128];
  __shared__ float s_t[NND][128];
  __shared__ float s_pool[128];
  __shared__ float s_h[64];
  for (int i = tid; i < NND * 16; i += 256) s_feat[i >> 4][i & 15] = feat[b * NND * 16 + i];
  __syncthreads();
  if (tid < NND) {
    float s = 0.f;
    for (int c = 0; c < 16; c++) s += s_feat[tid][c] * s_feat[tid][c];
    s_sq[tid] = s;
  }
  __syncthreads();
  for (int i = tid; i < NND * NND; i += 256) {
    int nn = i / NND, m = i % NND;
    float d = 0.f;
    for (int c = 0; c < 16; c++) d += s_feat[nn][c] * s_feat[m][c];
    s_dist[nn][m] = s_sq[nn] + s_sq[m] - 2.f * d;  // diagonal exactly 0
    s_adj[nn][m] = 0.f;
  }
  __syncthreads();
  if (tid < NND) {  // top-4 smallest per row, ties -> earliest index (matches top_k)
    unsigned used = 0;
    for (int j = 0; j < 4; j++) {
      float best = 3.4e38f; int bi = 0;
      for (int m = 0; m < NND; m++)
        if (!((used >> m) & 1u) && s_dist[tid][m] < best) { best = s_dist[tid][m]; bi = m; }
      used |= 1u << bi;
      s_adj[tid][bi] = 0.25f;
    }
  }
  __syncthreads();
  // ---- GCN layer 1: 16 -> 32 ----
  for (int i = tid; i < NND * 32; i += 256) {
    int nn = i / 32, f = i % 32;
    float a = 0.f;
    for (int c = 0; c < 16; c++) a += s_feat[nn][c] * gw1[c * 32 + f];
    s_t[nn][f] = a;
  }
  __syncthreads();
  for (int i = tid; i < NND * 32; i += 256) {
    int nn = i / 32, f = i % 32;
    float a = gb1[f];
    for (int m = 0; m < NND; m++) a += s_adj[nn][m] * s_t[m][f];
    s_x[nn][f] = fmaxf(a, 0.f);
  }
  __syncthreads();
  // ---- GCN layer 2: 32 -> 64 ----
  for (int i = tid; i < NND * 64; i += 256) {
    int nn = i / 64, f = i % 64;
    float a = 0.f;
    for (int c = 0; c < 32; c++) a += s_x[nn][c] * gw2[c * 64 + f];
    s_t[nn][f] = a;
  }
  __syncthreads();
  for (int i = tid; i < NND * 64; i += 256) {
    int nn = i / 64, f = i % 64;
    float a = gb2[f];
    for (int m = 0; m < NND; m++) a += s_adj[nn][m] * s_t[m][f];
    s_x[nn][f] = fmaxf(a, 0.f);
  }
  __syncthreads();
  // ---- GCN layer 3: 64 -> 128 ----
  for (int i = tid; i < NND * 128; i += 256) {
    int nn = i / 128, f = i % 128;
    float a = 0.f;
    for (int c = 0; c < 64; c++) a += s_x[nn][c] * gw3[c * 128 + f];
    s_t[nn][f] = a;
  }
  __syncthreads();
  for (int i = tid; i < NND * 128; i += 256) {
    int nn = i / 128, f = i % 128;
    float a = gb3[f];
    for (int m = 0; m < NND; m++) a += s_adj[nn][m] * s_t[m][f];
    s_x[nn][f] = fmaxf(a, 0.f);
  }
  __syncthreads();
  if (tid < 128) {
    float a = 0.f;
    for (int m = 0; m < NND; m++) a += s_x[m][tid];
    s_pool[tid] = a * (1.0f / (float)NND);
  }
  __syncthreads();
  if (tid < 64) {
    float a = fb1[tid];
    for (int c = 0; c < 128; c++) a += s_pool[c] * fw1[c * 64 + tid];
    s_h[tid] = a;
  }
  __syncthreads();
  if (tid < 4) {
    float a = fb2[tid];
    for (int c = 0; c < 64; c++) a += s_h[c] * fw2[c * 4 + tid];
    out[b * 4 + tid] = a;
  }
}

extern "C" void kernel_launch(void* const* d_in, const int* in_sizes, int n_in,
                              void* d_out, int out_size, void* d_ws, size_t ws_size,
                              hipStream_t stream) {
  (void)in_sizes; (void)n_in; (void)out_size; (void)ws_size;
  const float* x   = (const float*)d_in[0];
  const float* w1  = (const float*)d_in[1];
  const float* g1  = (const float*)d_in[2];
  const float* b1  = (const float*)d_in[3];
  const float* w2  = (const float*)d_in[4];
  const float* g2  = (const float*)d_in[5];
  const float* b2  = (const float*)d_in[6];
  const float* w3  = (const float*)d_in[7];
  const float* g3  = (const float*)d_in[8];
  const float* b3  = (const float*)d_in[9];
  const float* gw1 = (const float*)d_in[10];
  const float* gb1 = (const float*)d_in[11];
  const float* gw2 = (const float*)d_in[12];
  const float* gb2 = (const float*)d_in[13];
  const float* gw3 = (const float*)d_in[14];
  const float* gb3 = (const float*)d_in[15];
  const float* fw1 = (const float*)d_in[16];
  const float* fb1 = (const float*)d_in[17];
  const float* fw2 = (const float*)d_in[18];
  const float* fb2 = (const float*)d_in[19];

  float* ws = (float*)d_ws;
  const long H1 = (long)NND * BSZ * 4 * 1000;  // 22,528,000 floats
  const long H2 = (long)NND * BSZ * 8 * 500;   // 22,528,000 floats
  float* h1   = ws;
  float* h2   = h1 + H1;
  float* feat = h2 + H2;                        // B*N*16 = 90,112
  float* scs1 = feat + (long)BSZ * NND * 16;    // scale/shift, 22*64 each
  float* scs2 = scs1 + NND * 64;
  float* scs3 = scs2 + NND * 64;
  float* p1   = scs3 + NND * 64;                // 22*512 slots * 8
  float* p2   = p1 + (long)NND * 512 * 8;       // 22*256 slots * 16
  float* p3   = p2 + (long)NND * 256 * 16;      // 22*256 slots * 32

  // block 1: input x is (B, N, T): node stride T, batch stride N*T
  conv_statsR<1, 4, 2000, 256, 2, 4><<<dim3(2, BSZ, NND), dim3(256), 0, stream>>>(
      x, 2000, (long)NND * 2000, 0, w1, p1);
  stats_reduce<4, 512, 2000><<<dim3(NND), dim3(256), 0, stream>>>(p1, g1, b1, scs1);
  conv_bn_pool4<1, 4, 2000, 256><<<dim3(2, BSZ, NND), dim3(256), 0, stream>>>(
      x, 2000, (long)NND * 2000, 0, w1, scs1, h1);
  // block 2: h1 layout [n][b][4][1000]
  conv_statsR<4, 8, 1000, 256, 1, 4><<<dim3(1, BSZ, NND), dim3(256), 0, stream>>>(
      h1, (long)BSZ * 4000, 4000, 1000, w2, p2);
  stats_reduce<8, 256, 1000><<<dim3(NND), dim3(256), 0, stream>>>(p2, g2, b2, scs2);
  conv_bn_pool4<4, 8, 1000, 256><<<dim3(1, BSZ, NND), dim3(256), 0, stream>>>(
      h1, (long)BSZ * 4000, 4000, 1000, w2, scs2, h2);
  // block 3: h2 layout [n][b][8][500]; channel-split kernels (VGPR-bounded)
  conv_stats3_split<<<dim3(1, BSZ, NND), dim3(256), 0, stream>>>(
      h2, (long)BSZ * 4000, 4000, 500, w3, p3);
  stats_reduce<16, 256, 500><<<dim3(NND), dim3(256), 0, stream>>>(p3, g3, b3, scs3);
  conv_feat3_split<<<dim3(1, BSZ, NND), dim3(256), 0, stream>>>(
      h2, (long)BSZ * 4000, 4000, 500, w3, scs3, feat);
  // graph tail
  graph_head<<<dim3(BSZ), dim3(256), 0, stream>>>(
      feat, gw1, gb1, gw2, gb2, gw3, gb3, fw1, fb1, fw2, fb2, (float*)d_out);
}

// Round 8
// 377.043 us; speedup vs baseline: 17.0573x; 1.4336x over previous
//
#include <hip/hip_runtime.h>

#define BSZ 256
#define NND 22
#define BN_EPS 1e-5f

// ---------------------------------------------------------------------------
// Shared conv core: each thread computes R consecutive conv1d(k=7,pad=3)
// outputs from LDS-staged input and LDS-staged weights ([c][k][o] layout,
// float4-broadcast reads).
// c-loop is unroll-1 ON PURPOSE (R4/R5/R6 lesson, confirmed twice): full
// unroll at CIN>=4 hoists all LDS x/weight reads, blowing VGPR to 164-256
// -> occupancy 11% (or scratch spill at 256). unroll-1 bounds live state
// to ~one iteration (y + xr[10] + 2 weight float4s) ~= 80 VGPR.
// For CIN=1 unroll-1 is identical to full unroll.
// ---------------------------------------------------------------------------
template<int CIN, int COUT, int R, int SROW>
__device__ __forceinline__ void conv_coreR(
    const float (*s_in)[SROW], const float* s_w, int tid, float y[COUT][R]) {
#pragma unroll
  for (int o = 0; o < COUT; o++)
#pragma unroll
    for (int r = 0; r < R; r++) y[o][r] = 0.f;
#pragma unroll 1
  for (int c = 0; c < CIN; c++) {
    float xr[R + 6];
    if constexpr (R == 4) {
      const float4* xp = (const float4*)&s_in[c][4 * tid];  // 16B aligned
      float4 xa = xp[0], xb = xp[1];
      float2 xc = *(const float2*)&s_in[c][4 * tid + 8];    // 8B aligned
      xr[0] = xa.x; xr[1] = xa.y; xr[2] = xa.z; xr[3] = xa.w;
      xr[4] = xb.x; xr[5] = xb.y; xr[6] = xb.z; xr[7] = xb.w;
      xr[8] = xc.x; xr[9] = xc.y;
    } else {
      const float2* xp = (const float2*)&s_in[c][2 * tid];  // 8B aligned
      float2 x0 = xp[0], x1 = xp[1], x2 = xp[2], x3 = xp[3];
      xr[0] = x0.x; xr[1] = x0.y; xr[2] = x1.x; xr[3] = x1.y;
      xr[4] = x2.x; xr[5] = x2.y; xr[6] = x3.x; xr[7] = x3.y;
    }
#pragma unroll
    for (int k = 0; k < 7; k++) {
      const float4* wp = (const float4*)&s_w[(c * 7 + k) * COUT];
#pragma unroll
      for (int o4 = 0; o4 < COUT / 4; o4++) {
        float4 wv = wp[o4];
#pragma unroll
        for (int r = 0; r < R; r++) {
          y[4 * o4 + 0][r] += wv.x * xr[r + k];
          y[4 * o4 + 1][r] += wv.y * xr[r + k];
          y[4 * o4 + 2][r] += wv.z * xr[r + k];
          y[4 * o4 + 3][r] += wv.w * xr[r + k];
        }
      }
    }
  }
}

template<int CIN, int COUT, int NTH>
__device__ __forceinline__ void stage_weights(const float* __restrict__ w,
                                              float* s_w, int tid) {
  for (int i = tid; i < CIN * 7 * COUT; i += NTH) {
    int c = i / (7 * COUT), k = (i / COUT) % 7, o = i % COUT;
    s_w[i] = w[(o * CIN + c) * 7 + k];
  }
}

// ---------------------------------------------------------------------------
// Stats pass (CIN<=4): conv + per-channel sum/sum^2 -> private partial slot.
// grid: (NT, B, N), block NTH. TILE = R*NTH conv positions.
// ---------------------------------------------------------------------------
template<int CIN, int COUT, int LIN, int NTH, int NT, int R>
__global__ __launch_bounds__(NTH) void conv_statsR(
    const float* __restrict__ in, long sn, long sb, long sc,
    const float* __restrict__ w, float* __restrict__ part) {
  const int TILE = R * NTH;
  const int SROW = TILE + 8;
  __shared__ alignas(16) float s_in[CIN][SROW];
  __shared__ alignas(16) float s_w[CIN * 7 * COUT];
  __shared__ float s_red[2][NTH / 64][COUT];
  int tid = threadIdx.x, n = blockIdx.z, b = blockIdx.y;
  int t0 = blockIdx.x * TILE;
  const float* base = in + (long)n * sn + (long)b * sb;
  stage_weights<CIN, COUT, NTH>(w, s_w, tid);
  for (int c = 0; c < CIN; c++)
    for (int i = tid; i < TILE + 6; i += NTH) {
      int l = t0 + i - 3;
      s_in[c][i] = (l >= 0 && l < LIN) ? base[(long)c * sc + l] : 0.f;
    }
  __syncthreads();
  float y[COUT][R];
  conv_coreR<CIN, COUT, R, SROW>(s_in, s_w, tid, y);
  bool valid = (t0 + R * tid) < LIN;  // LIN % R == 0: all-or-nothing
  int lane = tid & 63, wv = tid >> 6;
#pragma unroll
  for (int o = 0; o < COUT; o++) {
    float s = 0.f, q = 0.f;
    if (valid) {
#pragma unroll
      for (int r = 0; r < R; r++) { s += y[o][r]; q += y[o][r] * y[o][r]; }
    }
#pragma unroll
    for (int off = 32; off > 0; off >>= 1) {
      s += __shfl_down(s, off, 64);
      q += __shfl_down(q, off, 64);
    }
    if (lane == 0) { s_red[0][wv][o] = s; s_red[1][wv][o] = q; }
  }
  __syncthreads();
  if (tid < COUT) {
    float s = 0.f, q = 0.f;
#pragma unroll
    for (int g = 0; g < NTH / 64; g++) { s += s_red[0][g][tid]; q += s_red[1][g][tid]; }
    long slot = ((long)n * NT + blockIdx.x) * BSZ + b;
    part[slot * (2 * COUT) + tid] = s;
    part[slot * (2 * COUT) + COUT + tid] = q;
  }
}

// ---------------------------------------------------------------------------
// Reduce partials -> BN scale/shift per (node, channel).
// scs layout: scs[n*64 + o] = scale, scs[n*64 + 32 + o] = shift
// ---------------------------------------------------------------------------
template<int C, int NSLOT, int LIN>
__global__ __launch_bounds__(256) void stats_reduce(
    const float* __restrict__ part,
    const float* __restrict__ gamma, const float* __restrict__ beta,
    float* __restrict__ scs) {
  const int V = 2 * C;
  const int GRP = 256 / V;
  int n = blockIdx.x, tid = threadIdx.x;
  int j = tid % V, g = tid / V;
  const float* p = part + (long)n * NSLOT * V;
  float s = 0.f;
  for (int sl = g; sl < NSLOT; sl += GRP) s += p[(long)sl * V + j];
  __shared__ float red[V][GRP];
  __shared__ float tot[V];
  red[j][g] = s;
  __syncthreads();
  if (tid < V) {
    float t = 0.f;
#pragma unroll
    for (int gg = 0; gg < GRP; gg++) t += red[tid][gg];
    tot[tid] = t;
  }
  __syncthreads();
  if (tid < C) {
    float cnt = (float)BSZ * (float)LIN;
    float m = tot[tid] / cnt;
    float var = tot[C + tid] / cnt - m * m;
    float istd = 1.0f / sqrtf(var + BN_EPS);
    float scl = gamma[tid] * istd;
    scs[n * 64 + tid] = scl;
    scs[n * 64 + 32 + tid] = beta[tid] - m * scl;
  }
}

// ---------------------------------------------------------------------------
// Apply pass (CIN<=4, R=4): conv + BN + ReLU + MaxPool(2), float2 store.
// grid: (NT, B, N), block NTH. outh layout [n][b][COUT][LP]
// ---------------------------------------------------------------------------
template<int CIN, int COUT, int LIN, int NTH>
__global__ __launch_bounds__(NTH) void conv_bn_pool4(
    const float* __restrict__ in, long sn, long sb, long sc,
    const float* __restrict__ w, const float* __restrict__ scs,
    float* __restrict__ outh) {
  const int LP = LIN / 2;
  const int TILE = 4 * NTH;
  const int SROW = TILE + 8;
  __shared__ alignas(16) float s_in[CIN][SROW];
  __shared__ alignas(16) float s_w[CIN * 7 * COUT];
  __shared__ float s_scale[COUT], s_shift[COUT];
  int tid = threadIdx.x, n = blockIdx.z, b = blockIdx.y;
  int P0 = blockIdx.x * (2 * NTH);
  int t0 = 2 * P0;
  const float* base = in + (long)n * sn + (long)b * sb;
  if (tid < COUT) {
    s_scale[tid] = scs[n * 64 + tid];
    s_shift[tid] = scs[n * 64 + 32 + tid];
  }
  stage_weights<CIN, COUT, NTH>(w, s_w, tid);
  for (int c = 0; c < CIN; c++)
    for (int i = tid; i < TILE + 6; i += NTH) {
      int l = t0 + i - 3;
      s_in[c][i] = (l >= 0 && l < LIN) ? base[(long)c * sc + l] : 0.f;
    }
  __syncthreads();
  float y[COUT][4];
  conv_coreR<CIN, COUT, 4, SROW>(s_in, s_w, tid, y);
  int pl = P0 + 2 * tid;
  if (pl >= LP) return;  // LP % 2 == 0: all-or-nothing
  long obase = ((long)n * BSZ + b) * COUT * (long)LP;
#pragma unroll
  for (int o = 0; o < COUT; o++) {
    float a0 = y[o][0] * s_scale[o] + s_shift[o];
    float a1 = y[o][1] * s_scale[o] + s_shift[o];
    float a2 = y[o][2] * s_scale[o] + s_shift[o];
    float a3 = y[o][3] * s_scale[o] + s_shift[o];
    float2 v;
    v.x = fmaxf(fmaxf(a0, a1), 0.f);
    v.y = fmaxf(fmaxf(a2, a3), 0.f);
    *(float2*)&outh[obase + (long)o * LP + pl] = v;
  }
}

// ---------------------------------------------------------------------------
// Block-3 stats (CIN=8, COUT=16): channel-split — 2 groups x 128 threads,
// group og handles channels og*8..og*8+7, 4 positions/thread (TILE=512>=500).
// c-loop unroll-1 (register-pressure bound). grid: (1, B, N), block 256.
// ---------------------------------------------------------------------------
__global__ __launch_bounds__(256) void conv_stats3_split(
    const float* __restrict__ in, long sn, long sb, long sc,
    const float* __restrict__ w, float* __restrict__ part) {
  const int LIN = 500, SROW = 512 + 8;
  __shared__ alignas(16) float s_in[8][SROW];
  __shared__ alignas(16) float s_w[8 * 7 * 16];
  __shared__ float s_red[2][4][8];
  int tid = threadIdx.x, n = blockIdx.z, b = blockIdx.y;
  int og = tid >> 7, pt = tid & 127;
  const float* base = in + (long)n * sn + (long)b * sb;
  stage_weights<8, 16, 256>(w, s_w, tid);
  for (int c = 0; c < 8; c++)
    for (int i = tid; i < 512 + 6; i += 256) {
      int l = i - 3;
      s_in[c][i] = (l >= 0 && l < LIN) ? base[(long)c * sc + l] : 0.f;
    }
  __syncthreads();
  float y[8][4];
#pragma unroll
  for (int o = 0; o < 8; o++)
#pragma unroll
    for (int r = 0; r < 4; r++) y[o][r] = 0.f;
#pragma unroll 1
  for (int c = 0; c < 8; c++) {
    const float4* xp = (const float4*)&s_in[c][4 * pt];
    float4 xa = xp[0], xb = xp[1];
    float2 xc = *(const float2*)&s_in[c][4 * pt + 8];
    float xr[10];
    xr[0] = xa.x; xr[1] = xa.y; xr[2] = xa.z; xr[3] = xa.w;
    xr[4] = xb.x; xr[5] = xb.y; xr[6] = xb.z; xr[7] = xb.w;
    xr[8] = xc.x; xr[9] = xc.y;
#pragma unroll
    for (int k = 0; k < 7; k++) {
      float4 w0 = *(const float4*)&s_w[(c * 7 + k) * 16 + og * 8];
      float4 w1 = *(const float4*)&s_w[(c * 7 + k) * 16 + og * 8 + 4];
#pragma unroll
      for (int r = 0; r < 4; r++) {
        y[0][r] += w0.x * xr[r + k];
        y[1][r] += w0.y * xr[r + k];
        y[2][r] += w0.z * xr[r + k];
        y[3][r] += w0.w * xr[r + k];
        y[4][r] += w1.x * xr[r + k];
        y[5][r] += w1.y * xr[r + k];
        y[6][r] += w1.z * xr[r + k];
        y[7][r] += w1.w * xr[r + k];
      }
    }
  }
  bool valid = (4 * pt) < LIN;  // 500 % 4 == 0: all-or-nothing
  int lane = tid & 63, wv = tid >> 6;  // og is wave-uniform (waves 0,1 / 2,3)
#pragma unroll
  for (int o = 0; o < 8; o++) {
    float s = 0.f, q = 0.f;
    if (valid) {
#pragma unroll
      for (int r = 0; r < 4; r++) { s += y[o][r]; q += y[o][r] * y[o][r]; }
    }
#pragma unroll
    for (int off = 32; off > 0; off >>= 1) {
      s += __shfl_down(s, off, 64);
      q += __shfl_down(q, off, 64);
    }
    if (lane == 0) { s_red[0][wv][o] = s; s_red[1][wv][o] = q; }
  }
  __syncthreads();
  if (tid < 16) {
    int og2 = tid >> 3, o = tid & 7;
    float s = s_red[0][2 * og2][o] + s_red[0][2 * og2 + 1][o];
    float q = s_red[1][2 * og2][o] + s_red[1][2 * og2 + 1][o];
    long slot = (long)n * BSZ + b;
    part[slot * 32 + tid] = s;
    part[slot * 32 + 16 + tid] = q;
  }
}

// ---------------------------------------------------------------------------
// Block-3 apply (CIN=8, COUT=16) fused with AdaptiveAvgPool -> feat[b][n][16].
// Same channel-split + unroll-1 structure. grid: (1, B, N), block 256.
// ---------------------------------------------------------------------------
__global__ __launch_bounds__(256) void conv_feat3_split(
    const float* __restrict__ in, long sn, long sb, long sc,
    const float* __restrict__ w, const float* __restrict__ scs,
    float* __restrict__ feat) {
  const int LIN = 500, LP = 250, SROW = 512 + 8;
  __shared__ alignas(16) float s_in[8][SROW];
  __shared__ alignas(16) float s_w[8 * 7 * 16];
  __shared__ float s_scale[16], s_shift[16];
  __shared__ float s_red[4][8];
  int tid = threadIdx.x, n = blockIdx.z, b = blockIdx.y;
  int og = tid >> 7, pt = tid & 127;
  const float* base = in + (long)n * sn + (long)b * sb;
  if (tid < 16) {
    s_scale[tid] = scs[n * 64 + tid];
    s_shift[tid] = scs[n * 64 + 32 + tid];
  }
  stage_weights<8, 16, 256>(w, s_w, tid);
  for (int c = 0; c < 8; c++)
    for (int i = tid; i < 512 + 6; i += 256) {
      int l = i - 3;
      s_in[c][i] = (l >= 0 && l < LIN) ? base[(long)c * sc + l] : 0.f;
    }
  __syncthreads();
  float y[8][4];
#pragma unroll
  for (int o = 0; o < 8; o++)
#pragma unroll
    for (int r = 0; r < 4; r++) y[o][r] = 0.f;
#pragma unroll 1
  for (int c = 0; c < 8; c++) {
    const float4* xp = (const float4*)&s_in[c][4 * pt];
    float4 xa = xp[0], xb = xp[1];
    float2 xc = *(const float2*)&s_in[c][4 * pt + 8];
    float xr[10];
    xr[0] = xa.x; xr[1] = xa.y; xr[2] = xa.z; xr[3] = xa.w;
    xr[4] = xb.x; xr[5] = xb.y; xr[6] = xb.z; xr[7] = xb.w;
    xr[8] = xc.x; xr[9] = xc.y;
#pragma unroll
    for (int k = 0; k < 7; k++) {
      float4 w0 = *(const float4*)&s_w[(c * 7 + k) * 16 + og * 8];
      float4 w1 = *(const float4*)&s_w[(c * 7 + k) * 16 + og * 8 + 4];
#pragma unroll
      for (int r = 0; r < 4; r++) {
        y[0][r] += w0.x * xr[r + k];
        y[1][r] += w0.y * xr[r + k];
        y[2][r] += w0.z * xr[r + k];
        y[3][r] += w0.w * xr[r + k];
        y[4][r] += w1.x * xr[r + k];
        y[5][r] += w1.y * xr[r + k];
        y[6][r] += w1.z * xr[r + k];
        y[7][r] += w1.w * xr[r + k];
      }
    }
  }
  bool valid = (2 * pt) < LP;
  int lane = tid & 63, wv = tid >> 6;
#pragma unroll
  for (int o = 0; o < 8; o++) {
    float s = 0.f;
    if (valid) {
      int ch = og * 8 + o;
      float a0 = y[o][0] * s_scale[ch] + s_shift[ch];
      float a1 = y[o][1] * s_scale[ch] + s_shift[ch];
      float a2 = y[o][2] * s_scale[ch] + s_shift[ch];
      float a3 = y[o][3] * s_scale[ch] + s_shift[ch];
      s = fmaxf(fmaxf(a0, a1), 0.f) + fmaxf(fmaxf(a2, a3), 0.f);
    }
#pragma unroll
    for (int off = 32; off > 0; off >>= 1) s += __shfl_down(s, off, 64);
    if (lane == 0) s_red[wv][o] = s;
  }
  __syncthreads();
  if (tid < 16) {
    int og2 = tid >> 3, o = tid & 7;
    float s = s_red[2 * og2][o] + s_red[2 * og2 + 1][o];
    feat[((long)b * NND + n) * 16 + tid] = s * (1.0f / (float)LP);
  }
}

// ---------------------------------------------------------------------------
// Graph tail: adjacency (top-4 incl self) + 3 GCN layers + node-mean + MLP head
// grid: (B), block: 256. One workgroup per batch element, all in LDS.
// ---------------------------------------------------------------------------
__global__ __launch_bounds__(256) void graph_head(
    const float* __restrict__ feat,
    const float* __restrict__ gw1, const float* __restrict__ gb1,
    const float* __restrict__ gw2, const float* __restrict__ gb2,
    const float* __restrict__ gw3, const float* __restrict__ gb3,
    const float* __restrict__ fw1, const float* __restrict__ fb1,
    const float* __restrict__ fw2, const float* __restrict__ fb2,
    float* __restrict__ out) {
  int b = blockIdx.x, tid = threadIdx.x;
  __shared__ float s_feat[NND][16];
  __shared__ float s_sq[NND];
  __shared__ float s_dist[NND][NND];
  __shared__ float s_adj[NND][NND];
  __shared__ float s_x[NND][128];
  __shared__ float s_t[NND][128];
  __shared__ float s_pool[128];
  __shared__ float s_h[64];
  for (int i = tid; i < NND * 16; i += 256) s_feat[i >> 4][i & 15] = feat[b * NND * 16 + i];
  __syncthreads();
  if (tid < NND) {
    float s = 0.f;
    for (int c = 0; c < 16; c++) s += s_feat[tid][c] * s_feat[tid][c];
    s_sq[tid] = s;
  }
  __syncthreads();
  for (int i = tid; i < NND * NND; i += 256) {
    int nn = i / NND, m = i % NND;
    float d = 0.f;
    for (int c = 0; c < 16; c++) d += s_feat[nn][c] * s_feat[m][c];
    s_dist[nn][m] = s_sq[nn] + s_sq[m] - 2.f * d;  // diagonal exactly 0
    s_adj[nn][m] = 0.f;
  }
  __syncthreads();
  if (tid < NND) {  // top-4 smallest per row, ties -> earliest index (matches top_k)
    unsigned used = 0;
    for (int j = 0; j < 4; j++) {
      float best = 3.4e38f; int bi = 0;
      for (int m = 0; m < NND; m++)
        if (!((used >> m) & 1u) && s_dist[tid][m] < best) { best = s_dist[tid][m]; bi = m; }
      used |= 1u << bi;
      s_adj[tid][bi] = 0.25f;
    }
  }
  __syncthreads();
  // ---- GCN layer 1: 16 -> 32 ----
  for (int i = tid; i < NND * 32; i += 256) {
    int nn = i / 32, f = i % 32;
    float a = 0.f;
    for (int c = 0; c < 16; c++) a += s_feat[nn][c] * gw1[c * 32 + f];
    s_t[nn][f] = a;
  }
  __syncthreads();
  for (int i = tid; i < NND * 32; i += 256) {
    int nn = i / 32, f = i % 32;
    float a = gb1[f];
    for (int m = 0; m < NND; m++) a += s_adj[nn][m] * s_t[m][f];
    s_x[nn][f] = fmaxf(a, 0.f);
  }
  __syncthreads();
  // ---- GCN layer 2: 32 -> 64 ----
  for (int i = tid; i < NND * 64; i += 256) {
    int nn = i / 64, f = i % 64;
    float a = 0.f;
    for (int c = 0; c < 32; c++) a += s_x[nn][c] * gw2[c * 64 + f];
    s_t[nn][f] = a;
  }
  __syncthreads();
  for (int i = tid; i < NND * 64; i += 256) {
    int nn = i / 64, f = i % 64;
    float a = gb2[f];
    for (int m = 0; m < NND; m++) a += s_adj[nn][m] * s_t[m][f];
    s_x[nn][f] = fmaxf(a, 0.f);
  }
  __syncthreads();
  // ---- GCN layer 3: 64 -> 128 ----
  for (int i = tid; i < NND * 128; i += 256) {
    int nn = i / 128, f = i % 128;
    float a = 0.f;
    for (int c = 0; c < 64; c++) a += s_x[nn][c] * gw3[c * 128 + f];
    s_t[nn][f] = a;
  }
  __syncthreads();
  for (int i = tid; i < NND * 128; i += 256) {
    int nn = i / 128, f = i % 128;
    float a = gb3[f];
    for (int m = 0; m < NND; m++) a += s_adj[nn][m] * s_t[m][f];
    s_x[nn][f] = fmaxf(a, 0.f);
  }
  __syncthreads();
  if (tid < 128) {
    float a = 0.f;
    for (int m = 0; m < NND; m++) a += s_x[m][tid];
    s_pool[tid] = a * (1.0f / (float)NND);
  }
  __syncthreads();
  if (tid < 64) {
    float a = fb1[tid];
    for (int c = 0; c < 128; c++) a += s_pool[c] * fw1[c * 64 + tid];
    s_h[tid] = a;
  }
  __syncthreads();
  if (tid < 4) {
    float a = fb2[tid];
    for (int c = 0; c < 64; c++) a += s_h[c] * fw2[c * 4 + tid];
    out[b * 4 + tid] = a;
  }
}

extern "C" void kernel_launch(void* const* d_in, const int* in_sizes, int n_in,
                              void* d_out, int out_size, void* d_ws, size_t ws_size,
                              hipStream_t stream) {
  (void)in_sizes; (void)n_in; (void)out_size; (void)ws_size;
  const float* x   = (const float*)d_in[0];
  const float* w1  = (const float*)d_in[1];
  const float* g1  = (const float*)d_in[2];
  const float* b1  = (const float*)d_in[3];
  const float* w2  = (const float*)d_in[4];
  const float* g2  = (const float*)d_in[5];
  const float* b2  = (const float*)d_in[6];
  const float* w3  = (const float*)d_in[7];
  const float* g3  = (const float*)d_in[8];
  const float* b3  = (const float*)d_in[9];
  const float* gw1 = (const float*)d_in[10];
  const float* gb1 = (const float*)d_in[11];
  const float* gw2 = (const float*)d_in[12];
  const float* gb2 = (const float*)d_in[13];
  const float* gw3 = (const float*)d_in[14];
  const float* gb3 = (const float*)d_in[15];
  const float* fw1 = (const float*)d_in[16];
  const float* fb1 = (const float*)d_in[17];
  const float* fw2 = (const float*)d_in[18];
  const float* fb2 = (const float*)d_in[19];

  float* ws = (float*)d_ws;
  const long H1 = (long)NND * BSZ * 4 * 1000;  // 22,528,000 floats
  const long H2 = (long)NND * BSZ * 8 * 500;   // 22,528,000 floats
  float* h1   = ws;
  float* h2   = h1 + H1;
  float* feat = h2 + H2;                        // B*N*16 = 90,112
  float* scs1 = feat + (long)BSZ * NND * 16;    // scale/shift, 22*64 each
  float* scs2 = scs1 + NND * 64;
  float* scs3 = scs2 + NND * 64;
  float* p1   = scs3 + NND * 64;                // 22*512 slots * 8
  float* p2   = p1 + (long)NND * 512 * 8;       // 22*256 slots * 16
  float* p3   = p2 + (long)NND * 256 * 16;      // 22*256 slots * 32

  // block 1: input x is (B, N, T): node stride T, batch stride N*T
  conv_statsR<1, 4, 2000, 256, 2, 4><<<dim3(2, BSZ, NND), dim3(256), 0, stream>>>(
      x, 2000, (long)NND * 2000, 0, w1, p1);
  stats_reduce<4, 512, 2000><<<dim3(NND), dim3(256), 0, stream>>>(p1, g1, b1, scs1);
  conv_bn_pool4<1, 4, 2000, 256><<<dim3(2, BSZ, NND), dim3(256), 0, stream>>>(
      x, 2000, (long)NND * 2000, 0, w1, scs1, h1);
  // block 2: h1 layout [n][b][4][1000]
  conv_statsR<4, 8, 1000, 256, 1, 4><<<dim3(1, BSZ, NND), dim3(256), 0, stream>>>(
      h1, (long)BSZ * 4000, 4000, 1000, w2, p2);
  stats_reduce<8, 256, 1000><<<dim3(NND), dim3(256), 0, stream>>>(p2, g2, b2, scs2);
  conv_bn_pool4<4, 8, 1000, 256><<<dim3(1, BSZ, NND), dim3(256), 0, stream>>>(
      h1, (long)BSZ * 4000, 4000, 1000, w2, scs2, h2);
  // block 3: h2 layout [n][b][8][500]; channel-split kernels (VGPR-bounded)
  conv_stats3_split<<<dim3(1, BSZ, NND), dim3(256), 0, stream>>>(
      h2, (long)BSZ * 4000, 4000, 500, w3, p3);
  stats_reduce<16, 256, 500><<<dim3(NND), dim3(256), 0, stream>>>(p3, g3, b3, scs3);
  conv_feat3_split<<<dim3(1, BSZ, NND), dim3(256), 0, stream>>>(
      h2, (long)BSZ * 4000, 4000, 500, w3, scs3, feat);
  // graph tail
  graph_head<<<dim3(BSZ), dim3(256), 0, stream>>>(
      feat, gw1, gb1, gw2, gb2, gw3, gb3, fw1, fb1, fw2, fb2, (float*)d_out);
}

// Round 9
// 294.988 us; speedup vs baseline: 21.8021x; 1.2782x over previous
//
#include <hip/hip_runtime.h>

#define BSZ 256
#define NND 22
#define BN_EPS 1e-5f

// ---------------------------------------------------------------------------
// conv core for CIN<=4 paths (used by S1). c-loop unroll-1 ON PURPOSE
// (R4-R7 lesson, confirmed 3x): full unroll at CIN>=4 blows VGPR to 164-256.
// ---------------------------------------------------------------------------
template<int CIN, int COUT, int R, int SROW>
__device__ __forceinline__ void conv_coreR(
    const float (*s_in)[SROW], const float* s_w, int tid, float y[COUT][R]) {
#pragma unroll
  for (int o = 0; o < COUT; o++)
#pragma unroll
    for (int r = 0; r < R; r++) y[o][r] = 0.f;
#pragma unroll 1
  for (int c = 0; c < CIN; c++) {
    float xr[R + 6];
    if constexpr (R == 4) {
      const float4* xp = (const float4*)&s_in[c][4 * tid];
      float4 xa = xp[0], xb = xp[1];
      float2 xc = *(const float2*)&s_in[c][4 * tid + 8];
      xr[0] = xa.x; xr[1] = xa.y; xr[2] = xa.z; xr[3] = xa.w;
      xr[4] = xb.x; xr[5] = xb.y; xr[6] = xb.z; xr[7] = xb.w;
      xr[8] = xc.x; xr[9] = xc.y;
    } else {
      const float2* xp = (const float2*)&s_in[c][2 * tid];
      float2 x0 = xp[0], x1 = xp[1], x2 = xp[2], x3 = xp[3];
      xr[0] = x0.x; xr[1] = x0.y; xr[2] = x1.x; xr[3] = x1.y;
      xr[4] = x2.x; xr[5] = x2.y; xr[6] = x3.x; xr[7] = x3.y;
    }
#pragma unroll
    for (int k = 0; k < 7; k++) {
      const float4* wp = (const float4*)&s_w[(c * 7 + k) * COUT];
#pragma unroll
      for (int o4 = 0; o4 < COUT / 4; o4++) {
        float4 wv = wp[o4];
#pragma unroll
        for (int r = 0; r < R; r++) {
          y[4 * o4 + 0][r] += wv.x * xr[r + k];
          y[4 * o4 + 1][r] += wv.y * xr[r + k];
          y[4 * o4 + 2][r] += wv.z * xr[r + k];
          y[4 * o4 + 3][r] += wv.w * xr[r + k];
        }
      }
    }
  }
}

template<int CIN, int COUT, int NTH>
__device__ __forceinline__ void stage_weights(const float* __restrict__ w,
                                              float* s_w, int tid) {
  for (int i = tid; i < CIN * 7 * COUT; i += NTH) {
    int c = i / (7 * COUT), k = (i / COUT) % 7, o = i % COUT;
    s_w[i] = w[(o * CIN + c) * 7 + k];
  }
}

// ---------------------------------------------------------------------------
// S1: stats of conv1 over x -> private partial slot. (unchanged, proven)
// grid: (NT, B, N), block NTH.
// ---------------------------------------------------------------------------
template<int CIN, int COUT, int LIN, int NTH, int NT, int R>
__global__ __launch_bounds__(NTH) void conv_statsR(
    const float* __restrict__ in, long sn, long sb, long sc,
    const float* __restrict__ w, float* __restrict__ part) {
  const int TILE = R * NTH;
  const int SROW = TILE + 8;
  __shared__ alignas(16) float s_in[CIN][SROW];
  __shared__ alignas(16) float s_w[CIN * 7 * COUT];
  __shared__ float s_red[2][NTH / 64][COUT];
  int tid = threadIdx.x, n = blockIdx.z, b = blockIdx.y;
  int t0 = blockIdx.x * TILE;
  const float* base = in + (long)n * sn + (long)b * sb;
  stage_weights<CIN, COUT, NTH>(w, s_w, tid);
  for (int c = 0; c < CIN; c++)
    for (int i = tid; i < TILE + 6; i += NTH) {
      int l = t0 + i - 3;
      s_in[c][i] = (l >= 0 && l < LIN) ? base[(long)c * sc + l] : 0.f;
    }
  __syncthreads();
  float y[COUT][R];
  conv_coreR<CIN, COUT, R, SROW>(s_in, s_w, tid, y);
  bool valid = (t0 + R * tid) < LIN;
  int lane = tid & 63, wv = tid >> 6;
#pragma unroll
  for (int o = 0; o < COUT; o++) {
    float s = 0.f, q = 0.f;
    if (valid) {
#pragma unroll
      for (int r = 0; r < R; r++) { s += y[o][r]; q += y[o][r] * y[o][r]; }
    }
#pragma unroll
    for (int off = 32; off > 0; off >>= 1) {
      s += __shfl_down(s, off, 64);
      q += __shfl_down(q, off, 64);
    }
    if (lane == 0) { s_red[0][wv][o] = s; s_red[1][wv][o] = q; }
  }
  __syncthreads();
  if (tid < COUT) {
    float s = 0.f, q = 0.f;
#pragma unroll
    for (int g = 0; g < NTH / 64; g++) { s += s_red[0][g][tid]; q += s_red[1][g][tid]; }
    long slot = ((long)n * NT + blockIdx.x) * BSZ + b;
    part[slot * (2 * COUT) + tid] = s;
    part[slot * (2 * COUT) + COUT + tid] = q;
  }
}

// ---------------------------------------------------------------------------
// Reduce partials -> BN scale/shift. scs[n*64+o]=scale, scs[n*64+32+o]=shift
// ---------------------------------------------------------------------------
template<int C, int NSLOT, int LIN>
__global__ __launch_bounds__(256) void stats_reduce(
    const float* __restrict__ part,
    const float* __restrict__ gamma, const float* __restrict__ beta,
    float* __restrict__ scs) {
  const int V = 2 * C;
  const int GRP = 256 / V;
  int n = blockIdx.x, tid = threadIdx.x;
  int j = tid % V, g = tid / V;
  const float* p = part + (long)n * NSLOT * V;
  float s = 0.f;
  for (int sl = g; sl < NSLOT; sl += GRP) s += p[(long)sl * V + j];
  __shared__ float red[V][GRP];
  __shared__ float tot[V];
  red[j][g] = s;
  __syncthreads();
  if (tid < V) {
    float t = 0.f;
#pragma unroll
    for (int gg = 0; gg < GRP; gg++) t += red[tid][gg];
    tot[tid] = t;
  }
  __syncthreads();
  if (tid < C) {
    float cnt = (float)BSZ * (float)LIN;
    float m = tot[tid] / cnt;
    float var = tot[C + tid] / cnt - m * m;
    float istd = 1.0f / sqrtf(var + BN_EPS);
    float scl = gamma[tid] * istd;
    scs[n * 64 + tid] = scl;
    scs[n * 64 + 32 + tid] = beta[tid] - m * scl;
  }
}

// ---------------------------------------------------------------------------
// F1: apply1 (conv1+BN1+ReLU+pool -> h1) FUSED with stats2 (conv2 over the
// in-LDS h1 row). One block per (n,b); full rows live in LDS so conv2 needs
// no halo exchange and h1 is read zero extra times for stats.
// grid: (1, B, N), block 256.
// ---------------------------------------------------------------------------
__global__ __launch_bounds__(256) void fused1(
    const float* __restrict__ x,      // (B, N, 2000)
    const float* __restrict__ w1,     // (4,1,7)
    const float* __restrict__ scs1,
    const float* __restrict__ w2,     // (8,4,7)
    float* __restrict__ h1,           // [n][b][4][1000]
    float* __restrict__ p2) {         // [(n*256+b)*16]
  __shared__ alignas(16) float s_x[2016];
  __shared__ alignas(16) float s_h1[4][1008];   // s_h1[c][j+3] = h1row[c][j]
  __shared__ alignas(16) float s_w1[28];        // [k][o]
  __shared__ alignas(16) float s_w2[224];       // [c][k][o]
  __shared__ float s_sc[4], s_sh[4];
  __shared__ float s_red[2][4][8];
  int tid = threadIdx.x, n = blockIdx.z, b = blockIdx.y;
  const float* xb = x + (long)b * (NND * 2000) + (long)n * 2000;
  if (tid < 28) { int k = tid >> 2, o = tid & 3; s_w1[tid] = w1[o * 7 + k]; }
  stage_weights<4, 8, 256>(w2, s_w2, tid);
  if (tid < 4) { s_sc[tid] = scs1[n * 64 + tid]; s_sh[tid] = scs1[n * 64 + 32 + tid]; }
  for (int i = tid; i < 2006; i += 256) {
    int l = i - 3;
    s_x[i] = (l >= 0 && l < 2000) ? xb[l] : 0.f;
  }
  __syncthreads();
  // ---- Phase A: conv1 (R=8) + BN1 + ReLU + pool -> h1 (global + LDS) ----
  if (tid < 250) {                                  // 8*250 = 2000 exactly
    float xr[14];
    const float4* xp = (const float4*)&s_x[8 * tid];
    float4 a = xp[0], bb = xp[1], c4 = xp[2];
    float2 d2 = *(const float2*)&s_x[8 * tid + 12];
    xr[0] = a.x; xr[1] = a.y; xr[2] = a.z; xr[3] = a.w;
    xr[4] = bb.x; xr[5] = bb.y; xr[6] = bb.z; xr[7] = bb.w;
    xr[8] = c4.x; xr[9] = c4.y; xr[10] = c4.z; xr[11] = c4.w;
    xr[12] = d2.x; xr[13] = d2.y;
    float y[4][8];
#pragma unroll
    for (int o = 0; o < 4; o++)
#pragma unroll
      for (int r = 0; r < 8; r++) y[o][r] = 0.f;
#pragma unroll
    for (int k = 0; k < 7; k++) {
      float4 wv = *(const float4*)&s_w1[k * 4];
#pragma unroll
      for (int r = 0; r < 8; r++) {
        y[0][r] += wv.x * xr[r + k];
        y[1][r] += wv.y * xr[r + k];
        y[2][r] += wv.z * xr[r + k];
        y[3][r] += wv.w * xr[r + k];
      }
    }
    long hb = ((long)n * BSZ + b) * 4000;
#pragma unroll
    for (int o = 0; o < 4; o++) {
      float4 v;
      float a0 = y[o][0] * s_sc[o] + s_sh[o], a1 = y[o][1] * s_sc[o] + s_sh[o];
      float a2 = y[o][2] * s_sc[o] + s_sh[o], a3 = y[o][3] * s_sc[o] + s_sh[o];
      float a4 = y[o][4] * s_sc[o] + s_sh[o], a5 = y[o][5] * s_sc[o] + s_sh[o];
      float a6 = y[o][6] * s_sc[o] + s_sh[o], a7 = y[o][7] * s_sc[o] + s_sh[o];
      v.x = fmaxf(fmaxf(a0, a1), 0.f);
      v.y = fmaxf(fmaxf(a2, a3), 0.f);
      v.z = fmaxf(fmaxf(a4, a5), 0.f);
      v.w = fmaxf(fmaxf(a6, a7), 0.f);
      *(float4*)&h1[hb + o * 1000 + 4 * tid] = v;
      s_h1[o][4 * tid + 3] = v.x;
      s_h1[o][4 * tid + 4] = v.y;
      s_h1[o][4 * tid + 5] = v.z;
      s_h1[o][4 * tid + 6] = v.w;
    }
  }
  if (tid < 3) {
#pragma unroll
    for (int o = 0; o < 4; o++) s_h1[o][tid] = 0.f;
  } else if (tid < 6) {
#pragma unroll
    for (int o = 0; o < 4; o++) s_h1[o][1000 + tid] = 0.f;
  }
  __syncthreads();
  // ---- Phase B: conv2 over in-LDS h1 -> stats2 partials ----
  float y2[8][4];
#pragma unroll
  for (int o = 0; o < 8; o++)
#pragma unroll
    for (int r = 0; r < 4; r++) y2[o][r] = 0.f;
  if (tid < 250) {                                  // 4*250 = 1000 exactly
#pragma unroll 1
    for (int c = 0; c < 4; c++) {
      const float4* xp = (const float4*)&s_h1[c][4 * tid];
      float4 xa = xp[0], xb2 = xp[1];
      float2 xc = *(const float2*)&s_h1[c][4 * tid + 8];
      float xr[10];
      xr[0] = xa.x; xr[1] = xa.y; xr[2] = xa.z; xr[3] = xa.w;
      xr[4] = xb2.x; xr[5] = xb2.y; xr[6] = xb2.z; xr[7] = xb2.w;
      xr[8] = xc.x; xr[9] = xc.y;
#pragma unroll
      for (int k = 0; k < 7; k++) {
        float4 w0 = *(const float4*)&s_w2[(c * 7 + k) * 8];
        float4 w1v = *(const float4*)&s_w2[(c * 7 + k) * 8 + 4];
#pragma unroll
        for (int r = 0; r < 4; r++) {
          y2[0][r] += w0.x * xr[r + k];
          y2[1][r] += w0.y * xr[r + k];
          y2[2][r] += w0.z * xr[r + k];
          y2[3][r] += w0.w * xr[r + k];
          y2[4][r] += w1v.x * xr[r + k];
          y2[5][r] += w1v.y * xr[r + k];
          y2[6][r] += w1v.z * xr[r + k];
          y2[7][r] += w1v.w * xr[r + k];
        }
      }
    }
  }
  int lane = tid & 63, wv = tid >> 6;
#pragma unroll
  for (int o = 0; o < 8; o++) {
    float s = y2[o][0] + y2[o][1] + y2[o][2] + y2[o][3];
    float q = y2[o][0] * y2[o][0] + y2[o][1] * y2[o][1] +
              y2[o][2] * y2[o][2] + y2[o][3] * y2[o][3];
#pragma unroll
    for (int off = 32; off > 0; off >>= 1) {
      s += __shfl_down(s, off, 64);
      q += __shfl_down(q, off, 64);
    }
    if (lane == 0) { s_red[0][wv][o] = s; s_red[1][wv][o] = q; }
  }
  __syncthreads();
  if (tid < 8) {
    float s = 0.f, q = 0.f;
#pragma unroll
    for (int g = 0; g < 4; g++) { s += s_red[0][g][tid]; q += s_red[1][g][tid]; }
    long slot = (long)n * BSZ + b;
    p2[slot * 16 + tid] = s;
    p2[slot * 16 + 8 + tid] = q;
  }
}

// ---------------------------------------------------------------------------
// F2: apply2 (conv2+BN2+ReLU+pool -> h2 in LDS ONLY) fused with conv3
// (channel-split) -> pooled raw conv3 to global (y3p) + stats3 partials.
// h2 never touches global memory. y3p stores the PAIRWISE MAX of raw conv3:
// valid because scale3 = gamma3*istd > 0 (gamma3 == 1 in the inputs), so
// maxpool∘relu∘BN == relu∘BN∘maxpool exactly.
// grid: (1, B, N), block 256.
// ---------------------------------------------------------------------------
__global__ __launch_bounds__(256) void fused2(
    const float* __restrict__ h1,     // [n][b][4][1000]
    const float* __restrict__ scs2,
    const float* __restrict__ w2,     // (8,4,7)
    const float* __restrict__ w3,     // (16,8,7)
    float* __restrict__ y3p,          // [n][b][16][250] pooled raw conv3
    float* __restrict__ p3) {         // [(n*256+b)*32]
  __shared__ alignas(16) float s_h1[4][1008];   // s_h1[c][j+3] = h1row
  __shared__ alignas(16) float s_h2[8][508];    // s_h2[c][j+3] = h2row
  __shared__ alignas(16) float s_w2[224];
  __shared__ alignas(16) float s_w3[896];
  __shared__ float s_sc[8], s_sh[8];
  __shared__ float s_red[2][4][8];
  int tid = threadIdx.x, n = blockIdx.z, b = blockIdx.y;
  const float* hb = h1 + ((long)n * BSZ + b) * 4000;
  stage_weights<4, 8, 256>(w2, s_w2, tid);
  stage_weights<8, 16, 256>(w3, s_w3, tid);
  if (tid < 8) { s_sc[tid] = scs2[n * 64 + tid]; s_sh[tid] = scs2[n * 64 + 32 + tid]; }
  for (int c = 0; c < 4; c++)
    for (int i = tid; i < 1006; i += 256) {
      int l = i - 3;
      s_h1[c][i] = (l >= 0 && l < 1000) ? hb[c * 1000 + l] : 0.f;
    }
  __syncthreads();
  // ---- Phase B: conv2 + BN2 + ReLU + pool -> s_h2 ----
  if (tid < 250) {                                  // 4*250 = 1000 exactly
    float y2[8][4];
#pragma unroll
    for (int o = 0; o < 8; o++)
#pragma unroll
      for (int r = 0; r < 4; r++) y2[o][r] = 0.f;
#pragma unroll 1
    for (int c = 0; c < 4; c++) {
      const float4* xp = (const float4*)&s_h1[c][4 * tid];
      float4 xa = xp[0], xb2 = xp[1];
      float2 xc = *(const float2*)&s_h1[c][4 * tid + 8];
      float xr[10];
      xr[0] = xa.x; xr[1] = xa.y; xr[2] = xa.z; xr[3] = xa.w;
      xr[4] = xb2.x; xr[5] = xb2.y; xr[6] = xb2.z; xr[7] = xb2.w;
      xr[8] = xc.x; xr[9] = xc.y;
#pragma unroll
      for (int k = 0; k < 7; k++) {
        float4 w0 = *(const float4*)&s_w2[(c * 7 + k) * 8];
        float4 w1v = *(const float4*)&s_w2[(c * 7 + k) * 8 + 4];
#pragma unroll
        for (int r = 0; r < 4; r++) {
          y2[0][r] += w0.x * xr[r + k];
          y2[1][r] += w0.y * xr[r + k];
          y2[2][r] += w0.z * xr[r + k];
          y2[3][r] += w0.w * xr[r + k];
          y2[4][r] += w1v.x * xr[r + k];
          y2[5][r] += w1v.y * xr[r + k];
          y2[6][r] += w1v.z * xr[r + k];
          y2[7][r] += w1v.w * xr[r + k];
        }
      }
    }
#pragma unroll
    for (int o = 0; o < 8; o++) {
      float a0 = y2[o][0] * s_sc[o] + s_sh[o];
      float a1 = y2[o][1] * s_sc[o] + s_sh[o];
      float a2 = y2[o][2] * s_sc[o] + s_sh[o];
      float a3 = y2[o][3] * s_sc[o] + s_sh[o];
      s_h2[o][2 * tid + 3] = fmaxf(fmaxf(a0, a1), 0.f);
      s_h2[o][2 * tid + 4] = fmaxf(fmaxf(a2, a3), 0.f);
    }
  }
  if (tid < 3) {
#pragma unroll
    for (int o = 0; o < 8; o++) s_h2[o][tid] = 0.f;
  } else if (tid < 6) {
#pragma unroll
    for (int o = 0; o < 8; o++) s_h2[o][500 + tid] = 0.f;
  }
  __syncthreads();
  // ---- Phase C: conv3 channel-split (2 groups x 128) over in-LDS h2 ----
  int og = tid >> 7, pt = tid & 127;
  bool valid = pt < 125;                            // 4*125 = 500 exactly
  float y3[8][4];
#pragma unroll
  for (int o = 0; o < 8; o++)
#pragma unroll
    for (int r = 0; r < 4; r++) y3[o][r] = 0.f;
  if (valid) {
#pragma unroll 1
    for (int c = 0; c < 8; c++) {
      const float4* xp = (const float4*)&s_h2[c][4 * pt];
      float4 xa = xp[0], xb2 = xp[1];
      float2 xc = *(const float2*)&s_h2[c][4 * pt + 8];
      float xr[10];
      xr[0] = xa.x; xr[1] = xa.y; xr[2] = xa.z; xr[3] = xa.w;
      xr[4] = xb2.x; xr[5] = xb2.y; xr[6] = xb2.z; xr[7] = xb2.w;
      xr[8] = xc.x; xr[9] = xc.y;
#pragma unroll
      for (int k = 0; k < 7; k++) {
        float4 w0 = *(const float4*)&s_w3[(c * 7 + k) * 16 + og * 8];
        float4 w1v = *(const float4*)&s_w3[(c * 7 + k) * 16 + og * 8 + 4];
#pragma unroll
        for (int r = 0; r < 4; r++) {
          y3[0][r] += w0.x * xr[r + k];
          y3[1][r] += w0.y * xr[r + k];
          y3[2][r] += w0.z * xr[r + k];
          y3[3][r] += w0.w * xr[r + k];
          y3[4][r] += w1v.x * xr[r + k];
          y3[5][r] += w1v.y * xr[r + k];
          y3[6][r] += w1v.z * xr[r + k];
          y3[7][r] += w1v.w * xr[r + k];
        }
      }
    }
    long yb = (((long)n * BSZ + b) * 16 + og * 8) * 250 + 2 * pt;
#pragma unroll
    for (int o = 0; o < 8; o++) {
      float2 v;
      v.x = fmaxf(y3[o][0], y3[o][1]);
      v.y = fmaxf(y3[o][2], y3[o][3]);
      *(float2*)&y3p[yb + o * 250] = v;
    }
  }
  int lane = tid & 63, wv = tid >> 6;
#pragma unroll
  for (int o = 0; o < 8; o++) {
    float s = y3[o][0] + y3[o][1] + y3[o][2] + y3[o][3];
    float q = y3[o][0] * y3[o][0] + y3[o][1] * y3[o][1] +
              y3[o][2] * y3[o][2] + y3[o][3] * y3[o][3];
#pragma unroll
    for (int off = 32; off > 0; off >>= 1) {
      s += __shfl_down(s, off, 64);
      q += __shfl_down(q, off, 64);
    }
    if (lane == 0) { s_red[0][wv][o] = s; s_red[1][wv][o] = q; }
  }
  __syncthreads();
  if (tid < 16) {
    int og2 = tid >> 3, o = tid & 7;
    float s = s_red[0][2 * og2][o] + s_red[0][2 * og2 + 1][o];
    float q = s_red[1][2 * og2][o] + s_red[1][2 * og2 + 1][o];
    long slot = (long)n * BSZ + b;
    p3[slot * 32 + tid] = s;
    p3[slot * 32 + 16 + tid] = q;
  }
}

// ---------------------------------------------------------------------------
// F3: BN3 + ReLU + avg over pooled raw conv3 -> feat[b][n][16].
// Memory-bound pass (90 MB). Uses scale3>0 (see fused2 comment).
// grid: (1, B, N), block 256 (16 chans x 16 threads).
// ---------------------------------------------------------------------------
__global__ __launch_bounds__(256) void feat_apply(
    const float* __restrict__ y3p,
    const float* __restrict__ scs3,
    float* __restrict__ feat) {
  int tid = threadIdx.x, n = blockIdx.z, b = blockIdx.y;
  int ch = tid >> 4, s = tid & 15;
  const float* yb = y3p + (((long)n * BSZ + b) * 16 + ch) * 250;
  float sc = scs3[n * 64 + ch], sh = scs3[n * 64 + 32 + ch];
  float acc = 0.f;
  for (int j = s; j < 125; j += 16) {
    float2 v = *(const float2*)&yb[2 * j];
    acc += fmaxf(v.x * sc + sh, 0.f) + fmaxf(v.y * sc + sh, 0.f);
  }
#pragma unroll
  for (int off = 8; off > 0; off >>= 1) acc += __shfl_down(acc, off, 16);
  if (s == 0) feat[((long)b * NND + n) * 16 + ch] = acc * (1.0f / 250.f);
}

// ---------------------------------------------------------------------------
// Graph tail: adjacency (top-4 incl self) + 3 GCN layers + node-mean + MLP
// grid: (B), block: 256.
// ---------------------------------------------------------------------------
__global__ __launch_bounds__(256) void graph_head(
    const float* __restrict__ feat,
    const float* __restrict__ gw1, const float* __restrict__ gb1,
    const float* __restrict__ gw2, const float* __restrict__ gb2,
    const float* __restrict__ gw3, const float* __restrict__ gb3,
    const float* __restrict__ fw1, const float* __restrict__ fb1,
    const float* __restrict__ fw2, const float* __restrict__ fb2,
    float* __restrict__ out) {
  int b = blockIdx.x, tid = threadIdx.x;
  __shared__ float s_feat[NND][16];
  __shared__ float s_sq[NND];
  __shared__ float s_dist[NND][NND];
  __shared__ float s_adj[NND][NND];
  __shared__ float s_x[NND][128];
  __shared__ float s_t[NND][128];
  __shared__ float s_pool[128];
  __shared__ float s_h[64];
  for (int i = tid; i < NND * 16; i += 256) s_feat[i >> 4][i & 15] = feat[b * NND * 16 + i];
  __syncthreads();
  if (tid < NND) {
    float s = 0.f;
    for (int c = 0; c < 16; c++) s += s_feat[tid][c] * s_feat[tid][c];
    s_sq[tid] = s;
  }
  __syncthreads();
  for (int i = tid; i < NND * NND; i += 256) {
    int nn = i / NND, m = i % NND;
    float d = 0.f;
    for (int c = 0; c < 16; c++) d += s_feat[nn][c] * s_feat[m][c];
    s_dist[nn][m] = s_sq[nn] + s_sq[m] - 2.f * d;  // diagonal exactly 0
    s_adj[nn][m] = 0.f;
  }
  __syncthreads();
  if (tid < NND) {  // top-4 smallest, ties -> earliest index (matches top_k)
    unsigned used = 0;
    for (int j = 0; j < 4; j++) {
      float best = 3.4e38f; int bi = 0;
      for (int m = 0; m < NND; m++)
        if (!((used >> m) & 1u) && s_dist[tid][m] < best) { best = s_dist[tid][m]; bi = m; }
      used |= 1u << bi;
      s_adj[tid][bi] = 0.25f;
    }
  }
  __syncthreads();
  for (int i = tid; i < NND * 32; i += 256) {
    int nn = i / 32, f = i % 32;
    float a = 0.f;
    for (int c = 0; c < 16; c++) a += s_feat[nn][c] * gw1[c * 32 + f];
    s_t[nn][f] = a;
  }
  __syncthreads();
  for (int i = tid; i < NND * 32; i += 256) {
    int nn = i / 32, f = i % 32;
    float a = gb1[f];
    for (int m = 0; m < NND; m++) a += s_adj[nn][m] * s_t[m][f];
    s_x[nn][f] = fmaxf(a, 0.f);
  }
  __syncthreads();
  for (int i = tid; i < NND * 64; i += 256) {
    int nn = i / 64, f = i % 64;
    float a = 0.f;
    for (int c = 0; c < 32; c++) a += s_x[nn][c] * gw2[c * 64 + f];
    s_t[nn][f] = a;
  }
  __syncthreads();
  for (int i = tid; i < NND * 64; i += 256) {
    int nn = i / 64, f = i % 64;
    float a = gb2[f];
    for (int m = 0; m < NND; m++) a += s_adj[nn][m] * s_t[m][f];
    s_x[nn][f] = fmaxf(a, 0.f);
  }
  __syncthreads();
  for (int i = tid; i < NND * 128; i += 256) {
    int nn = i / 128, f = i % 128;
    float a = 0.f;
    for (int c = 0; c < 64; c++) a += s_x[nn][c] * gw3[c * 128 + f];
    s_t[nn][f] = a;
  }
  __syncthreads();
  for (int i = tid; i < NND * 128; i += 256) {
    int nn = i / 128, f = i % 128;
    float a = gb3[f];
    for (int m = 0; m < NND; m++) a += s_adj[nn][m] * s_t[m][f];
    s_x[nn][f] = fmaxf(a, 0.f);
  }
  __syncthreads();
  if (tid < 128) {
    float a = 0.f;
    for (int m = 0; m < NND; m++) a += s_x[m][tid];
    s_pool[tid] = a * (1.0f / (float)NND);
  }
  __syncthreads();
  if (tid < 64) {
    float a = fb1[tid];
    for (int c = 0; c < 128; c++) a += s_pool[c] * fw1[c * 64 + tid];
    s_h[tid] = a;
  }
  __syncthreads();
  if (tid < 4) {
    float a = fb2[tid];
    for (int c = 0; c < 64; c++) a += s_h[c] * fw2[c * 4 + tid];
    out[b * 4 + tid] = a;
  }
}

extern "C" void kernel_launch(void* const* d_in, const int* in_sizes, int n_in,
                              void* d_out, int out_size, void* d_ws, size_t ws_size,
                              hipStream_t stream) {
  (void)in_sizes; (void)n_in; (void)out_size; (void)ws_size;
  const float* x   = (const float*)d_in[0];
  const float* w1  = (const float*)d_in[1];
  const float* g1  = (const float*)d_in[2];
  const float* b1  = (const float*)d_in[3];
  const float* w2  = (const float*)d_in[4];
  const float* g2  = (const float*)d_in[5];
  const float* b2  = (const float*)d_in[6];
  const float* w3  = (const float*)d_in[7];
  const float* g3  = (const float*)d_in[8];
  const float* b3  = (const float*)d_in[9];
  const float* gw1 = (const float*)d_in[10];
  const float* gb1 = (const float*)d_in[11];
  const float* gw2 = (const float*)d_in[12];
  const float* gb2 = (const float*)d_in[13];
  const float* gw3 = (const float*)d_in[14];
  const float* gb3 = (const float*)d_in[15];
  const float* fw1 = (const float*)d_in[16];
  const float* fb1 = (const float*)d_in[17];
  const float* fw2 = (const float*)d_in[18];
  const float* fb2 = (const float*)d_in[19];

  float* ws = (float*)d_ws;
  const long H1 = (long)NND * BSZ * 4 * 1000;   // 22,528,000 floats
  const long Y3 = (long)NND * BSZ * 16 * 250;   // 22,528,000 floats
  float* h1   = ws;
  float* y3p  = h1 + H1;
  float* feat = y3p + Y3;                       // B*N*16 = 90,112
  float* scs1 = feat + (long)BSZ * NND * 16;
  float* scs2 = scs1 + NND * 64;
  float* scs3 = scs2 + NND * 64;
  float* p1   = scs3 + NND * 64;                // 22*512 slots * 8
  float* p2   = p1 + (long)NND * 512 * 8;       // 22*256 slots * 16
  float* p3   = p2 + (long)NND * 256 * 16;      // 22*256 slots * 32
  // total ws ~= 182 MB (same budget as prior passing rounds)

  // stats1 over x
  conv_statsR<1, 4, 2000, 256, 2, 4><<<dim3(2, BSZ, NND), dim3(256), 0, stream>>>(
      x, 2000, (long)NND * 2000, 0, w1, p1);
  stats_reduce<4, 512, 2000><<<dim3(NND), dim3(256), 0, stream>>>(p1, g1, b1, scs1);
  // apply1 + stats2 (fused)
  fused1<<<dim3(1, BSZ, NND), dim3(256), 0, stream>>>(x, w1, scs1, w2, h1, p2);
  stats_reduce<8, 256, 1000><<<dim3(NND), dim3(256), 0, stream>>>(p2, g2, b2, scs2);
  // apply2 + conv3 (pooled raw out) + stats3 (fused)
  fused2<<<dim3(1, BSZ, NND), dim3(256), 0, stream>>>(h1, scs2, w2, w3, y3p, p3);
  stats_reduce<16, 256, 500><<<dim3(NND), dim3(256), 0, stream>>>(p3, g3, b3, scs3);
  // BN3 + ReLU + avg -> feat
  feat_apply<<<dim3(1, BSZ, NND), dim3(256), 0, stream>>>(y3p, scs3, feat);
  // graph tail
  graph_head<<<dim3(BSZ), dim3(256), 0, stream>>>(
      feat, gw1, gb1, gw2, gb2, gw3, gb3, fw1, fb1, fw2, fb2, (float*)d_out);
}

// Round 10
// 247.084 us; speedup vs baseline: 26.0290x; 1.1939x over previous
//
#include <hip/hip_runtime.h>

#define BSZ 256
#define NND 22
#define BN_EPS 1e-5f

// ---------------------------------------------------------------------------
// conv core for CIN<=4 (used by S1). c-loop unroll-1 ON PURPOSE (R4-R7
// lesson, confirmed 3x): full unroll at CIN>=4 blows VGPR to 164-256.
// ---------------------------------------------------------------------------
template<int CIN, int COUT, int R, int SROW>
__device__ __forceinline__ void conv_coreR(
    const float (*s_in)[SROW], const float* s_w, int tid, float y[COUT][R]) {
#pragma unroll
  for (int o = 0; o < COUT; o++)
#pragma unroll
    for (int r = 0; r < R; r++) y[o][r] = 0.f;
#pragma unroll 1
  for (int c = 0; c < CIN; c++) {
    float xr[R + 6];
    if constexpr (R == 4) {
      const float4* xp = (const float4*)&s_in[c][4 * tid];
      float4 xa = xp[0], xb = xp[1];
      float2 xc = *(const float2*)&s_in[c][4 * tid + 8];
      xr[0] = xa.x; xr[1] = xa.y; xr[2] = xa.z; xr[3] = xa.w;
      xr[4] = xb.x; xr[5] = xb.y; xr[6] = xb.z; xr[7] = xb.w;
      xr[8] = xc.x; xr[9] = xc.y;
    } else {
      const float2* xp = (const float2*)&s_in[c][2 * tid];
      float2 x0 = xp[0], x1 = xp[1], x2 = xp[2], x3 = xp[3];
      xr[0] = x0.x; xr[1] = x0.y; xr[2] = x1.x; xr[3] = x1.y;
      xr[4] = x2.x; xr[5] = x2.y; xr[6] = x3.x; xr[7] = x3.y;
    }
#pragma unroll
    for (int k = 0; k < 7; k++) {
      const float4* wp = (const float4*)&s_w[(c * 7 + k) * COUT];
#pragma unroll
      for (int o4 = 0; o4 < COUT / 4; o4++) {
        float4 wv = wp[o4];
#pragma unroll
        for (int r = 0; r < R; r++) {
          y[4 * o4 + 0][r] += wv.x * xr[r + k];
          y[4 * o4 + 1][r] += wv.y * xr[r + k];
          y[4 * o4 + 2][r] += wv.z * xr[r + k];
          y[4 * o4 + 3][r] += wv.w * xr[r + k];
        }
      }
    }
  }
}

template<int CIN, int COUT, int NTH>
__device__ __forceinline__ void stage_weights(const float* __restrict__ w,
                                              float* s_w, int tid) {
  for (int i = tid; i < CIN * 7 * COUT; i += NTH) {
    int c = i / (7 * COUT), k = (i / COUT) % 7, o = i % COUT;
    s_w[i] = w[(o * CIN + c) * 7 + k];
  }
}

// ---------------------------------------------------------------------------
// S1: stats of conv1 over x -> private partial slot. (unchanged, proven)
// ---------------------------------------------------------------------------
template<int CIN, int COUT, int LIN, int NTH, int NT, int R>
__global__ __launch_bounds__(NTH) void conv_statsR(
    const float* __restrict__ in, long sn, long sb, long sc,
    const float* __restrict__ w, float* __restrict__ part) {
  const int TILE = R * NTH;
  const int SROW = TILE + 8;
  __shared__ alignas(16) float s_in[CIN][SROW];
  __shared__ alignas(16) float s_w[CIN * 7 * COUT];
  __shared__ float s_red[2][NTH / 64][COUT];
  int tid = threadIdx.x, n = blockIdx.z, b = blockIdx.y;
  int t0 = blockIdx.x * TILE;
  const float* base = in + (long)n * sn + (long)b * sb;
  stage_weights<CIN, COUT, NTH>(w, s_w, tid);
  for (int c = 0; c < CIN; c++)
    for (int i = tid; i < TILE + 6; i += NTH) {
      int l = t0 + i - 3;
      s_in[c][i] = (l >= 0 && l < LIN) ? base[(long)c * sc + l] : 0.f;
    }
  __syncthreads();
  float y[COUT][R];
  conv_coreR<CIN, COUT, R, SROW>(s_in, s_w, tid, y);
  bool valid = (t0 + R * tid) < LIN;
  int lane = tid & 63, wv = tid >> 6;
#pragma unroll
  for (int o = 0; o < COUT; o++) {
    float s = 0.f, q = 0.f;
    if (valid) {
#pragma unroll
      for (int r = 0; r < R; r++) { s += y[o][r]; q += y[o][r] * y[o][r]; }
    }
#pragma unroll
    for (int off = 32; off > 0; off >>= 1) {
      s += __shfl_down(s, off, 64);
      q += __shfl_down(q, off, 64);
    }
    if (lane == 0) { s_red[0][wv][o] = s; s_red[1][wv][o] = q; }
  }
  __syncthreads();
  if (tid < COUT) {
    float s = 0.f, q = 0.f;
#pragma unroll
    for (int g = 0; g < NTH / 64; g++) { s += s_red[0][g][tid]; q += s_red[1][g][tid]; }
    long slot = ((long)n * NT + blockIdx.x) * BSZ + b;
    part[slot * (2 * COUT) + tid] = s;
    part[slot * (2 * COUT) + COUT + tid] = q;
  }
}

// ---------------------------------------------------------------------------
// Reduce partials -> BN scale/shift. scs[n*64+o]=scale, scs[n*64+32+o]=shift
// ---------------------------------------------------------------------------
template<int C, int NSLOT, int LIN>
__global__ __launch_bounds__(256) void stats_reduce(
    const float* __restrict__ part,
    const float* __restrict__ gamma, const float* __restrict__ beta,
    float* __restrict__ scs) {
  const int V = 2 * C;
  const int GRP = 256 / V;
  int n = blockIdx.x, tid = threadIdx.x;
  int j = tid % V, g = tid / V;
  const float* p = part + (long)n * NSLOT * V;
  float s = 0.f;
  for (int sl = g; sl < NSLOT; sl += GRP) s += p[(long)sl * V + j];
  __shared__ float red[V][GRP];
  __shared__ float tot[V];
  red[j][g] = s;
  __syncthreads();
  if (tid < V) {
    float t = 0.f;
#pragma unroll
    for (int gg = 0; gg < GRP; gg++) t += red[tid][gg];
    tot[tid] = t;
  }
  __syncthreads();
  if (tid < C) {
    float cnt = (float)BSZ * (float)LIN;
    float m = tot[tid] / cnt;
    float var = tot[C + tid] / cnt - m * m;
    float istd = 1.0f / sqrtf(var + BN_EPS);
    float scl = gamma[tid] * istd;
    scs[n * 64 + tid] = scl;
    scs[n * 64 + 32 + tid] = beta[tid] - m * scl;
  }
}

// ---------------------------------------------------------------------------
// F1: conv1+BN1+ReLU+pool -> h1 (LDS ONLY) -> conv2 -> pooled raw conv2 to
// global (y2p, pairwise max — valid since scale2 = gamma2*istd > 0, gamma==1,
// so maxpool∘relu∘BN == relu∘BN∘maxpool exactly) + stats2 partials.
// h1 never touches global memory. All LDS halos are 4-wide so every staging
// write / conv read is a 16B-aligned lane-consecutive b128 (conflict-free).
// grid: (1, B, N), block 256.
// ---------------------------------------------------------------------------
__global__ __launch_bounds__(256) void fused1(
    const float* __restrict__ x,      // (B, N, 2000)
    const float* __restrict__ w1,     // (4,1,7)
    const float* __restrict__ scs1,
    const float* __restrict__ w2,     // (8,4,7)
    float* __restrict__ y2p,          // [n][b][8][500] pooled raw conv2
    float* __restrict__ p2) {         // [(n*256+b)*16]
  __shared__ alignas(16) float s_x[2016];       // s_x[j+4] = x[j]
  __shared__ alignas(16) float s_h1[4][1008];   // s_h1[c][j+4] = h1row[c][j]
  __shared__ alignas(16) float s_w1[28];        // [k][o]
  __shared__ alignas(16) float s_w2[224];       // [c][k][o]
  __shared__ float s_sc[4], s_sh[4];
  __shared__ float s_red[2][4][8];
  int tid = threadIdx.x, n = blockIdx.z, b = blockIdx.y;
  const float* xb = x + (long)b * (NND * 2000) + (long)n * 2000;
  if (tid < 28) { int k = tid >> 2, o = tid & 3; s_w1[tid] = w1[o * 7 + k]; }
  stage_weights<4, 8, 256>(w2, s_w2, tid);
  if (tid < 4) { s_sc[tid] = scs1[n * 64 + tid]; s_sh[tid] = scs1[n * 64 + 32 + tid]; }
  for (int i = tid; i < 500; i += 256)
    *(float4*)&s_x[4 * i + 4] = *(const float4*)&xb[4 * i];
  if (tid == 0) {
    *(float4*)&s_x[0] = make_float4(0.f, 0.f, 0.f, 0.f);
    *(float4*)&s_x[2004] = make_float4(0.f, 0.f, 0.f, 0.f);
  }
  __syncthreads();
  // ---- Phase A: conv1 (8 pos/thread) + BN1 + ReLU + pool -> s_h1 ----
  if (tid < 250) {                                  // 8*250 = 2000 exactly
    float xr[16];
    const float4* xp = (const float4*)&s_x[8 * tid];
#pragma unroll
    for (int v = 0; v < 4; v++) {
      float4 t = xp[v];
      xr[4 * v + 0] = t.x; xr[4 * v + 1] = t.y;
      xr[4 * v + 2] = t.z; xr[4 * v + 3] = t.w;
    }
    float y[4][8];
#pragma unroll
    for (int o = 0; o < 4; o++)
#pragma unroll
      for (int r = 0; r < 8; r++) y[o][r] = 0.f;
#pragma unroll
    for (int k = 0; k < 7; k++) {
      float4 wv = *(const float4*)&s_w1[k * 4];
#pragma unroll
      for (int r = 0; r < 8; r++) {
        y[0][r] += wv.x * xr[r + k + 1];
        y[1][r] += wv.y * xr[r + k + 1];
        y[2][r] += wv.z * xr[r + k + 1];
        y[3][r] += wv.w * xr[r + k + 1];
      }
    }
#pragma unroll
    for (int o = 0; o < 4; o++) {
      float a0 = y[o][0] * s_sc[o] + s_sh[o], a1 = y[o][1] * s_sc[o] + s_sh[o];
      float a2 = y[o][2] * s_sc[o] + s_sh[o], a3 = y[o][3] * s_sc[o] + s_sh[o];
      float a4 = y[o][4] * s_sc[o] + s_sh[o], a5 = y[o][5] * s_sc[o] + s_sh[o];
      float a6 = y[o][6] * s_sc[o] + s_sh[o], a7 = y[o][7] * s_sc[o] + s_sh[o];
      float4 v;
      v.x = fmaxf(fmaxf(a0, a1), 0.f);
      v.y = fmaxf(fmaxf(a2, a3), 0.f);
      v.z = fmaxf(fmaxf(a4, a5), 0.f);
      v.w = fmaxf(fmaxf(a6, a7), 0.f);
      *(float4*)&s_h1[o][4 * tid + 4] = v;      // 16B-aligned, conflict-free
    }
  }
  if (tid < 4) {
    *(float4*)&s_h1[tid][0] = make_float4(0.f, 0.f, 0.f, 0.f);
    *(float4*)&s_h1[tid][1004] = make_float4(0.f, 0.f, 0.f, 0.f);
  }
  __syncthreads();
  // ---- Phase B: conv2 over in-LDS h1 -> stats2 + pooled raw y2p ----
  float y2[8][4];
#pragma unroll
  for (int o = 0; o < 8; o++)
#pragma unroll
    for (int r = 0; r < 4; r++) y2[o][r] = 0.f;
  if (tid < 250) {                                  // 4*250 = 1000 exactly
#pragma unroll 1
    for (int c = 0; c < 4; c++) {
      float xr[12];
      const float4* xp = (const float4*)&s_h1[c][4 * tid];
#pragma unroll
      for (int v = 0; v < 3; v++) {
        float4 t = xp[v];
        xr[4 * v + 0] = t.x; xr[4 * v + 1] = t.y;
        xr[4 * v + 2] = t.z; xr[4 * v + 3] = t.w;
      }
#pragma unroll
      for (int k = 0; k < 7; k++) {
        float4 w0 = *(const float4*)&s_w2[(c * 7 + k) * 8];
        float4 w1v = *(const float4*)&s_w2[(c * 7 + k) * 8 + 4];
#pragma unroll
        for (int r = 0; r < 4; r++) {
          float xv = xr[r + k + 1];
          y2[0][r] += w0.x * xv;
          y2[1][r] += w0.y * xv;
          y2[2][r] += w0.z * xv;
          y2[3][r] += w0.w * xv;
          y2[4][r] += w1v.x * xv;
          y2[5][r] += w1v.y * xv;
          y2[6][r] += w1v.z * xv;
          y2[7][r] += w1v.w * xv;
        }
      }
    }
    long yb = ((long)n * BSZ + b) * 4000 + 2 * tid;
#pragma unroll
    for (int o = 0; o < 8; o++) {
      float2 v;
      v.x = fmaxf(y2[o][0], y2[o][1]);
      v.y = fmaxf(y2[o][2], y2[o][3]);
      *(float2*)&y2p[yb + o * 500] = v;
    }
  }
  int lane = tid & 63, wv = tid >> 6;
#pragma unroll
  for (int o = 0; o < 8; o++) {
    float s = y2[o][0] + y2[o][1] + y2[o][2] + y2[o][3];
    float q = y2[o][0] * y2[o][0] + y2[o][1] * y2[o][1] +
              y2[o][2] * y2[o][2] + y2[o][3] * y2[o][3];
#pragma unroll
    for (int off = 32; off > 0; off >>= 1) {
      s += __shfl_down(s, off, 64);
      q += __shfl_down(q, off, 64);
    }
    if (lane == 0) { s_red[0][wv][o] = s; s_red[1][wv][o] = q; }
  }
  __syncthreads();
  if (tid < 8) {
    float s = 0.f, q = 0.f;
#pragma unroll
    for (int g = 0; g < 4; g++) { s += s_red[0][g][tid]; q += s_red[1][g][tid]; }
    long slot = (long)n * BSZ + b;
    p2[slot * 16 + tid] = s;
    p2[slot * 16 + 8 + tid] = q;
  }
}

// ---------------------------------------------------------------------------
// F2: read y2p, BN2+ReLU (scale2>0 commutes with the stored pairwise max)
// -> h2 in LDS, then conv3 (channel-split, 2 groups x 128) -> pooled raw
// conv3 (y3p) + stats3 partials. NO conv2 recompute (the R9 157us kernel's
// phase B is gone). grid: (1, B, N), block 256.
// ---------------------------------------------------------------------------
__global__ __launch_bounds__(256) void fused2(
    const float* __restrict__ y2p,    // [n][b][8][500]
    const float* __restrict__ scs2,
    const float* __restrict__ w3,     // (16,8,7)
    float* __restrict__ y3p,          // [n][b][16][250] pooled raw conv3
    float* __restrict__ p3) {         // [(n*256+b)*32]
  __shared__ alignas(16) float s_h2[8][512];    // s_h2[c][j+4] = h2row[c][j]
  __shared__ alignas(16) float s_w3[896];
  __shared__ float s_sc[8], s_sh[8];
  __shared__ float s_red[2][4][8];
  int tid = threadIdx.x, n = blockIdx.z, b = blockIdx.y;
  stage_weights<8, 16, 256>(w3, s_w3, tid);
  if (tid < 8) { s_sc[tid] = scs2[n * 64 + tid]; s_sh[tid] = scs2[n * 64 + 32 + tid]; }
  __syncthreads();
  // stage + BN2 + ReLU -> s_h2 (b128 aligned writes, conflict-free)
  const float* yb2 = y2p + ((long)n * BSZ + b) * 4000;
  for (int i = tid; i < 1000; i += 256) {
    int ch = i / 125, j4 = i % 125;
    float4 v = *(const float4*)&yb2[ch * 500 + 4 * j4];
    float sc = s_sc[ch], sh = s_sh[ch];
    v.x = fmaxf(v.x * sc + sh, 0.f);
    v.y = fmaxf(v.y * sc + sh, 0.f);
    v.z = fmaxf(v.z * sc + sh, 0.f);
    v.w = fmaxf(v.w * sc + sh, 0.f);
    *(float4*)&s_h2[ch][4 * j4 + 4] = v;
  }
  if (tid < 8) {
    *(float4*)&s_h2[tid][0] = make_float4(0.f, 0.f, 0.f, 0.f);
    *(float4*)&s_h2[tid][504] = make_float4(0.f, 0.f, 0.f, 0.f);
  }
  __syncthreads();
  // conv3 channel-split over in-LDS h2
  int og = tid >> 7, pt = tid & 127;
  bool valid = pt < 125;                            // 4*125 = 500 exactly
  float y3[8][4];
#pragma unroll
  for (int o = 0; o < 8; o++)
#pragma unroll
    for (int r = 0; r < 4; r++) y3[o][r] = 0.f;
  if (valid) {
#pragma unroll 1
    for (int c = 0; c < 8; c++) {
      float xr[12];
      const float4* xp = (const float4*)&s_h2[c][4 * pt];
#pragma unroll
      for (int v = 0; v < 3; v++) {
        float4 t = xp[v];
        xr[4 * v + 0] = t.x; xr[4 * v + 1] = t.y;
        xr[4 * v + 2] = t.z; xr[4 * v + 3] = t.w;
      }
#pragma unroll
      for (int k = 0; k < 7; k++) {
        float4 w0 = *(const float4*)&s_w3[(c * 7 + k) * 16 + og * 8];
        float4 w1v = *(const float4*)&s_w3[(c * 7 + k) * 16 + og * 8 + 4];
#pragma unroll
        for (int r = 0; r < 4; r++) {
          float xv = xr[r + k + 1];
          y3[0][r] += w0.x * xv;
          y3[1][r] += w0.y * xv;
          y3[2][r] += w0.z * xv;
          y3[3][r] += w0.w * xv;
          y3[4][r] += w1v.x * xv;
          y3[5][r] += w1v.y * xv;
          y3[6][r] += w1v.z * xv;
          y3[7][r] += w1v.w * xv;
        }
      }
    }
    long yb = (((long)n * BSZ + b) * 16 + og * 8) * 250 + 2 * pt;
#pragma unroll
    for (int o = 0; o < 8; o++) {
      float2 v;
      v.x = fmaxf(y3[o][0], y3[o][1]);
      v.y = fmaxf(y3[o][2], y3[o][3]);
      *(float2*)&y3p[yb + o * 250] = v;
    }
  }
  int lane = tid & 63, wv = tid >> 6;
#pragma unroll
  for (int o = 0; o < 8; o++) {
    float s = y3[o][0] + y3[o][1] + y3[o][2] + y3[o][3];
    float q = y3[o][0] * y3[o][0] + y3[o][1] * y3[o][1] +
              y3[o][2] * y3[o][2] + y3[o][3] * y3[o][3];
#pragma unroll
    for (int off = 32; off > 0; off >>= 1) {
      s += __shfl_down(s, off, 64);
      q += __shfl_down(q, off, 64);
    }
    if (lane == 0) { s_red[0][wv][o] = s; s_red[1][wv][o] = q; }
  }
  __syncthreads();
  if (tid < 16) {
    int og2 = tid >> 3, o = tid & 7;
    float s = s_red[0][2 * og2][o] + s_red[0][2 * og2 + 1][o];
    float q = s_red[1][2 * og2][o] + s_red[1][2 * og2 + 1][o];
    long slot = (long)n * BSZ + b;
    p3[slot * 32 + tid] = s;
    p3[slot * 32 + 16 + tid] = q;
  }
}

// ---------------------------------------------------------------------------
// F3: BN3 + ReLU + avg over pooled raw conv3 -> feat[b][n][16].
// grid: (1, B, N), block 256 (16 chans x 16 threads).
// ---------------------------------------------------------------------------
__global__ __launch_bounds__(256) void feat_apply(
    const float* __restrict__ y3p,
    const float* __restrict__ scs3,
    float* __restrict__ feat) {
  int tid = threadIdx.x, n = blockIdx.z, b = blockIdx.y;
  int ch = tid >> 4, s = tid & 15;
  const float* yb = y3p + (((long)n * BSZ + b) * 16 + ch) * 250;
  float sc = scs3[n * 64 + ch], sh = scs3[n * 64 + 32 + ch];
  float acc = 0.f;
  for (int j = s; j < 125; j += 16) {
    float2 v = *(const float2*)&yb[2 * j];
    acc += fmaxf(v.x * sc + sh, 0.f) + fmaxf(v.y * sc + sh, 0.f);
  }
#pragma unroll
  for (int off = 8; off > 0; off >>= 1) acc += __shfl_down(acc, off, 16);
  if (s == 0) feat[((long)b * NND + n) * 16 + ch] = acc * (1.0f / 250.f);
}

// ---------------------------------------------------------------------------
// Graph tail: adjacency (top-4 incl self) + 3 GCN layers + node-mean + MLP
// grid: (B), block: 256.
// ---------------------------------------------------------------------------
__global__ __launch_bounds__(256) void graph_head(
    const float* __restrict__ feat,
    const float* __restrict__ gw1, const float* __restrict__ gb1,
    const float* __restrict__ gw2, const float* __restrict__ gb2,
    const float* __restrict__ gw3, const float* __restrict__ gb3,
    const float* __restrict__ fw1, const float* __restrict__ fb1,
    const float* __restrict__ fw2, const float* __restrict__ fb2,
    float* __restrict__ out) {
  int b = blockIdx.x, tid = threadIdx.x;
  __shared__ float s_feat[NND][16];
  __shared__ float s_sq[NND];
  __shared__ float s_dist[NND][NND];
  __shared__ float s_adj[NND][NND];
  __shared__ float s_x[NND][128];
  __shared__ float s_t[NND][128];
  __shared__ float s_pool[128];
  __shared__ float s_h[64];
  for (int i = tid; i < NND * 16; i += 256) s_feat[i >> 4][i & 15] = feat[b * NND * 16 + i];
  __syncthreads();
  if (tid < NND) {
    float s = 0.f;
    for (int c = 0; c < 16; c++) s += s_feat[tid][c] * s_feat[tid][c];
    s_sq[tid] = s;
  }
  __syncthreads();
  for (int i = tid; i < NND * NND; i += 256) {
    int nn = i / NND, m = i % NND;
    float d = 0.f;
    for (int c = 0; c < 16; c++) d += s_feat[nn][c] * s_feat[m][c];
    s_dist[nn][m] = s_sq[nn] + s_sq[m] - 2.f * d;  // diagonal exactly 0
    s_adj[nn][m] = 0.f;
  }
  __syncthreads();
  if (tid < NND) {  // top-4 smallest, ties -> earliest index (matches top_k)
    unsigned used = 0;
    for (int j = 0; j < 4; j++) {
      float best = 3.4e38f; int bi = 0;
      for (int m = 0; m < NND; m++)
        if (!((used >> m) & 1u) && s_dist[tid][m] < best) { best = s_dist[tid][m]; bi = m; }
      used |= 1u << bi;
      s_adj[tid][bi] = 0.25f;
    }
  }
  __syncthreads();
  for (int i = tid; i < NND * 32; i += 256) {
    int nn = i / 32, f = i % 32;
    float a = 0.f;
    for (int c = 0; c < 16; c++) a += s_feat[nn][c] * gw1[c * 32 + f];
    s_t[nn][f] = a;
  }
  __syncthreads();
  for (int i = tid; i < NND * 32; i += 256) {
    int nn = i / 32, f = i % 32;
    float a = gb1[f];
    for (int m = 0; m < NND; m++) a += s_adj[nn][m] * s_t[m][f];
    s_x[nn][f] = fmaxf(a, 0.f);
  }
  __syncthreads();
  for (int i = tid; i < NND * 64; i += 256) {
    int nn = i / 64, f = i % 64;
    float a = 0.f;
    for (int c = 0; c < 32; c++) a += s_x[nn][c] * gw2[c * 64 + f];
    s_t[nn][f] = a;
  }
  __syncthreads();
  for (int i = tid; i < NND * 64; i += 256) {
    int nn = i / 64, f = i % 64;
    float a = gb2[f];
    for (int m = 0; m < NND; m++) a += s_adj[nn][m] * s_t[m][f];
    s_x[nn][f] = fmaxf(a, 0.f);
  }
  __syncthreads();
  for (int i = tid; i < NND * 128; i += 256) {
    int nn = i / 128, f = i % 128;
    float a = 0.f;
    for (int c = 0; c < 64; c++) a += s_x[nn][c] * gw3[c * 128 + f];
    s_t[nn][f] = a;
  }
  __syncthreads();
  for (int i = tid; i < NND * 128; i += 256) {
    int nn = i / 128, f = i % 128;
    float a = gb3[f];
    for (int m = 0; m < NND; m++) a += s_adj[nn][m] * s_t[m][f];
    s_x[nn][f] = fmaxf(a, 0.f);
  }
  __syncthreads();
  if (tid < 128) {
    float a = 0.f;
    for (int m = 0; m < NND; m++) a += s_x[m][tid];
    s_pool[tid] = a * (1.0f / (float)NND);
  }
  __syncthreads();
  if (tid < 64) {
    float a = fb1[tid];
    for (int c = 0; c < 128; c++) a += s_pool[c] * fw1[c * 64 + tid];
    s_h[tid] = a;
  }
  __syncthreads();
  if (tid < 4) {
    float a = fb2[tid];
    for (int c = 0; c < 64; c++) a += s_h[c] * fw2[c * 4 + tid];
    out[b * 4 + tid] = a;
  }
}

extern "C" void kernel_launch(void* const* d_in, const int* in_sizes, int n_in,
                              void* d_out, int out_size, void* d_ws, size_t ws_size,
                              hipStream_t stream) {
  (void)in_sizes; (void)n_in; (void)out_size; (void)ws_size;
  const float* x   = (const float*)d_in[0];
  const float* w1  = (const float*)d_in[1];
  const float* g1  = (const float*)d_in[2];
  const float* b1  = (const float*)d_in[3];
  const float* w2  = (const float*)d_in[4];
  const float* g2  = (const float*)d_in[5];
  const float* b2  = (const float*)d_in[6];
  const float* w3  = (const float*)d_in[7];
  const float* g3  = (const float*)d_in[8];
  const float* b3  = (const float*)d_in[9];
  const float* gw1 = (const float*)d_in[10];
  const float* gb1 = (const float*)d_in[11];
  const float* gw2 = (const float*)d_in[12];
  const float* gb2 = (const float*)d_in[13];
  const float* gw3 = (const float*)d_in[14];
  const float* gb3 = (const float*)d_in[15];
  const float* fw1 = (const float*)d_in[16];
  const float* fb1 = (const float*)d_in[17];
  const float* fw2 = (const float*)d_in[18];
  const float* fb2 = (const float*)d_in[19];

  float* ws = (float*)d_ws;
  const long Y2 = (long)NND * BSZ * 8 * 500;    // 22,528,000 floats
  const long Y3 = (long)NND * BSZ * 16 * 250;   // 22,528,000 floats
  float* y2p  = ws;
  float* y3p  = y2p + Y2;
  float* feat = y3p + Y3;                       // B*N*16 = 90,112
  float* scs1 = feat + (long)BSZ * NND * 16;
  float* scs2 = scs1 + NND * 64;
  float* scs3 = scs2 + NND * 64;
  float* p1   = scs3 + NND * 64;                // 22*512 slots * 8
  float* p2   = p1 + (long)NND * 512 * 8;       // 22*256 slots * 16
  float* p3   = p2 + (long)NND * 256 * 16;      // 22*256 slots * 32
  // total ws ~= 182 MB (same budget as prior passing rounds)

  // stats1 over x
  conv_statsR<1, 4, 2000, 256, 2, 4><<<dim3(2, BSZ, NND), dim3(256), 0, stream>>>(
      x, 2000, (long)NND * 2000, 0, w1, p1);
  stats_reduce<4, 512, 2000><<<dim3(NND), dim3(256), 0, stream>>>(p1, g1, b1, scs1);
  // conv1-apply + conv2 (pooled raw out) + stats2 (fused; h1 stays in LDS)
  fused1<<<dim3(1, BSZ, NND), dim3(256), 0, stream>>>(x, w1, scs1, w2, y2p, p2);
  stats_reduce<8, 256, 1000><<<dim3(NND), dim3(256), 0, stream>>>(p2, g2, b2, scs2);
  // BN2-apply + conv3 (pooled raw out) + stats3 (fused; no conv2 recompute)
  fused2<<<dim3(1, BSZ, NND), dim3(256), 0, stream>>>(y2p, scs2, w3, y3p, p3);
  stats_reduce<16, 256, 500><<<dim3(NND), dim3(256), 0, stream>>>(p3, g3, b3, scs3);
  // BN3 + ReLU + avg -> feat
  feat_apply<<<dim3(1, BSZ, NND), dim3(256), 0, stream>>>(y3p, scs3, feat);
  // graph tail
  graph_head<<<dim3(BSZ), dim3(256), 0, stream>>>(
      feat, gw1, gb1, gw2, gb2, gw3, gb3, fw1, fb1, fw2, fb2, (float*)d_out);
}

// Round 11
// 222.703 us; speedup vs baseline: 28.8786x; 1.1095x over previous
//
#include <hip/hip_runtime.h>

#define BSZ 256
#define NND 22
#define BN_EPS 1e-5f

// ---------------------------------------------------------------------------
// conv core for CIN<=4 (used by S1). c-loop unroll-1 ON PURPOSE (R4-R7
// lesson, confirmed 3x): full unroll at CIN>=4 blows VGPR to 164-256.
// ---------------------------------------------------------------------------
template<int CIN, int COUT, int R, int SROW>
__device__ __forceinline__ void conv_coreR(
    const float (*s_in)[SROW], const float* s_w, int tid, float y[COUT][R]) {
#pragma unroll
  for (int o = 0; o < COUT; o++)
#pragma unroll
    for (int r = 0; r < R; r++) y[o][r] = 0.f;
#pragma unroll 1
  for (int c = 0; c < CIN; c++) {
    float xr[R + 6];
    if constexpr (R == 4) {
      const float4* xp = (const float4*)&s_in[c][4 * tid];
      float4 xa = xp[0], xb = xp[1];
      float2 xc = *(const float2*)&s_in[c][4 * tid + 8];
      xr[0] = xa.x; xr[1] = xa.y; xr[2] = xa.z; xr[3] = xa.w;
      xr[4] = xb.x; xr[5] = xb.y; xr[6] = xb.z; xr[7] = xb.w;
      xr[8] = xc.x; xr[9] = xc.y;
    } else {
      const float2* xp = (const float2*)&s_in[c][2 * tid];
      float2 x0 = xp[0], x1 = xp[1], x2 = xp[2], x3 = xp[3];
      xr[0] = x0.x; xr[1] = x0.y; xr[2] = x1.x; xr[3] = x1.y;
      xr[4] = x2.x; xr[5] = x2.y; xr[6] = x3.x; xr[7] = x3.y;
    }
#pragma unroll
    for (int k = 0; k < 7; k++) {
      const float4* wp = (const float4*)&s_w[(c * 7 + k) * COUT];
#pragma unroll
      for (int o4 = 0; o4 < COUT / 4; o4++) {
        float4 wv = wp[o4];
#pragma unroll
        for (int r = 0; r < R; r++) {
          y[4 * o4 + 0][r] += wv.x * xr[r + k];
          y[4 * o4 + 1][r] += wv.y * xr[r + k];
          y[4 * o4 + 2][r] += wv.z * xr[r + k];
          y[4 * o4 + 3][r] += wv.w * xr[r + k];
        }
      }
    }
  }
}

template<int CIN, int COUT, int NTH>
__device__ __forceinline__ void stage_weights(const float* __restrict__ w,
                                              float* s_w, int tid) {
  for (int i = tid; i < CIN * 7 * COUT; i += NTH) {
    int c = i / (7 * COUT), k = (i / COUT) % 7, o = i % COUT;
    s_w[i] = w[(o * CIN + c) * 7 + k];
  }
}

// ---------------------------------------------------------------------------
// Pre-transpose conv2/conv3 weights to [c][k][o] contiguous in global so the
// conv loops can read them via wave-uniform s_load (scalar pipe) instead of
// LDS broadcasts (R10 lesson: 14 of 17 LDS b128s per c-iter were weights).
// ---------------------------------------------------------------------------
__global__ __launch_bounds__(256) void prep_weights(
    const float* __restrict__ w2, const float* __restrict__ w3,
    float* __restrict__ w2t, float* __restrict__ w3t) {
  int tid = threadIdx.x;
  if (tid < 224) {
    int c = tid / 56, k = (tid / 8) % 7, o = tid & 7;
    w2t[tid] = w2[(o * 4 + c) * 7 + k];
  }
  for (int i = tid; i < 896; i += 256) {
    int c = i / 112, k = (i / 16) % 7, o = i & 15;
    w3t[i] = w3[(o * 8 + c) * 7 + k];
  }
}

// ---------------------------------------------------------------------------
// S1: stats of conv1 over x -> private partial slot. (unchanged, proven)
// ---------------------------------------------------------------------------
template<int CIN, int COUT, int LIN, int NTH, int NT, int R>
__global__ __launch_bounds__(NTH) void conv_statsR(
    const float* __restrict__ in, long sn, long sb, long sc,
    const float* __restrict__ w, float* __restrict__ part) {
  const int TILE = R * NTH;
  const int SROW = TILE + 8;
  __shared__ alignas(16) float s_in[CIN][SROW];
  __shared__ alignas(16) float s_w[CIN * 7 * COUT];
  __shared__ float s_red[2][NTH / 64][COUT];
  int tid = threadIdx.x, n = blockIdx.z, b = blockIdx.y;
  int t0 = blockIdx.x * TILE;
  const float* base = in + (long)n * sn + (long)b * sb;
  stage_weights<CIN, COUT, NTH>(w, s_w, tid);
  for (int c = 0; c < CIN; c++)
    for (int i = tid; i < TILE + 6; i += NTH) {
      int l = t0 + i - 3;
      s_in[c][i] = (l >= 0 && l < LIN) ? base[(long)c * sc + l] : 0.f;
    }
  __syncthreads();
  float y[COUT][R];
  conv_coreR<CIN, COUT, R, SROW>(s_in, s_w, tid, y);
  bool valid = (t0 + R * tid) < LIN;
  int lane = tid & 63, wv = tid >> 6;
#pragma unroll
  for (int o = 0; o < COUT; o++) {
    float s = 0.f, q = 0.f;
    if (valid) {
#pragma unroll
      for (int r = 0; r < R; r++) { s += y[o][r]; q += y[o][r] * y[o][r]; }
    }
#pragma unroll
    for (int off = 32; off > 0; off >>= 1) {
      s += __shfl_down(s, off, 64);
      q += __shfl_down(q, off, 64);
    }
    if (lane == 0) { s_red[0][wv][o] = s; s_red[1][wv][o] = q; }
  }
  __syncthreads();
  if (tid < COUT) {
    float s = 0.f, q = 0.f;
#pragma unroll
    for (int g = 0; g < NTH / 64; g++) { s += s_red[0][g][tid]; q += s_red[1][g][tid]; }
    long slot = ((long)n * NT + blockIdx.x) * BSZ + b;
    part[slot * (2 * COUT) + tid] = s;
    part[slot * (2 * COUT) + COUT + tid] = q;
  }
}

// ---------------------------------------------------------------------------
// Reduce partials -> BN scale/shift. scs[n*64+o]=scale, scs[n*64+32+o]=shift
// ---------------------------------------------------------------------------
template<int C, int NSLOT, int LIN>
__global__ __launch_bounds__(256) void stats_reduce(
    const float* __restrict__ part,
    const float* __restrict__ gamma, const float* __restrict__ beta,
    float* __restrict__ scs) {
  const int V = 2 * C;
  const int GRP = 256 / V;
  int n = blockIdx.x, tid = threadIdx.x;
  int j = tid % V, g = tid / V;
  const float* p = part + (long)n * NSLOT * V;
  float s = 0.f;
  for (int sl = g; sl < NSLOT; sl += GRP) s += p[(long)sl * V + j];
  __shared__ float red[V][GRP];
  __shared__ float tot[V];
  red[j][g] = s;
  __syncthreads();
  if (tid < V) {
    float t = 0.f;
#pragma unroll
    for (int gg = 0; gg < GRP; gg++) t += red[tid][gg];
    tot[tid] = t;
  }
  __syncthreads();
  if (tid < C) {
    float cnt = (float)BSZ * (float)LIN;
    float m = tot[tid] / cnt;
    float var = tot[C + tid] / cnt - m * m;
    float istd = 1.0f / sqrtf(var + BN_EPS);
    float scl = gamma[tid] * istd;
    scs[n * 64 + tid] = scl;
    scs[n * 64 + 32 + tid] = beta[tid] - m * scl;
  }
}

// ---------------------------------------------------------------------------
// F1: conv1+BN1+ReLU+pool -> h1 (LDS ONLY) -> conv2 -> pooled raw conv2 to
// global (y2p, pairwise max; scale2>0 so maxpool∘relu∘BN == relu∘BN∘maxpool)
// + stats2 partials. Weights from SGPRs (uniform global loads), not LDS.
// grid: (1, B, N), block 256.
// ---------------------------------------------------------------------------
__global__ __launch_bounds__(256) void fused1(
    const float* __restrict__ x,      // (B, N, 2000)
    const float* __restrict__ w1,     // (4,1,7)
    const float* __restrict__ scs1,
    const float* __restrict__ w2t,    // [c][k][o] transposed conv2 weights
    float* __restrict__ y2p,          // [n][b][8][500] pooled raw conv2
    float* __restrict__ p2) {         // [(n*256+b)*16]
  __shared__ alignas(16) float s_x[2016];       // s_x[j+4] = x[j]
  __shared__ alignas(16) float s_h1[4][1008];   // s_h1[c][j+4] = h1row[c][j]
  __shared__ float s_sc[4], s_sh[4];
  __shared__ float s_red[2][4][8];
  int tid = threadIdx.x, n = blockIdx.z, b = blockIdx.y;
  const float* xb = x + (long)b * (NND * 2000) + (long)n * 2000;
  if (tid < 4) { s_sc[tid] = scs1[n * 64 + tid]; s_sh[tid] = scs1[n * 64 + 32 + tid]; }
  for (int i = tid; i < 500; i += 256)
    *(float4*)&s_x[4 * i + 4] = *(const float4*)&xb[4 * i];
  if (tid == 0) {
    *(float4*)&s_x[0] = make_float4(0.f, 0.f, 0.f, 0.f);
    *(float4*)&s_x[2004] = make_float4(0.f, 0.f, 0.f, 0.f);
  }
  __syncthreads();
  // ---- Phase A: conv1 (8 pos/thread) + BN1 + ReLU + pool -> s_h1 ----
  if (tid < 250) {                                  // 8*250 = 2000 exactly
    float xr[16];
    const float4* xp = (const float4*)&s_x[8 * tid];
#pragma unroll
    for (int v = 0; v < 4; v++) {
      float4 t = xp[v];
      xr[4 * v + 0] = t.x; xr[4 * v + 1] = t.y;
      xr[4 * v + 2] = t.z; xr[4 * v + 3] = t.w;
    }
    float y[4][8];
#pragma unroll
    for (int o = 0; o < 4; o++)
#pragma unroll
      for (int r = 0; r < 8; r++) y[o][r] = 0.f;
#pragma unroll
    for (int k = 0; k < 7; k++) {
      // uniform global loads -> SGPRs (hoisted by compiler)
      float w0 = w1[0 * 7 + k], w1v = w1[1 * 7 + k];
      float w2v = w1[2 * 7 + k], w3v = w1[3 * 7 + k];
#pragma unroll
      for (int r = 0; r < 8; r++) {
        y[0][r] += w0 * xr[r + k + 1];
        y[1][r] += w1v * xr[r + k + 1];
        y[2][r] += w2v * xr[r + k + 1];
        y[3][r] += w3v * xr[r + k + 1];
      }
    }
#pragma unroll
    for (int o = 0; o < 4; o++) {
      float a0 = y[o][0] * s_sc[o] + s_sh[o], a1 = y[o][1] * s_sc[o] + s_sh[o];
      float a2 = y[o][2] * s_sc[o] + s_sh[o], a3 = y[o][3] * s_sc[o] + s_sh[o];
      float a4 = y[o][4] * s_sc[o] + s_sh[o], a5 = y[o][5] * s_sc[o] + s_sh[o];
      float a6 = y[o][6] * s_sc[o] + s_sh[o], a7 = y[o][7] * s_sc[o] + s_sh[o];
      float4 v;
      v.x = fmaxf(fmaxf(a0, a1), 0.f);
      v.y = fmaxf(fmaxf(a2, a3), 0.f);
      v.z = fmaxf(fmaxf(a4, a5), 0.f);
      v.w = fmaxf(fmaxf(a6, a7), 0.f);
      *(float4*)&s_h1[o][4 * tid + 4] = v;      // 16B-aligned, conflict-free
    }
  }
  if (tid < 4) {
    *(float4*)&s_h1[tid][0] = make_float4(0.f, 0.f, 0.f, 0.f);
    *(float4*)&s_h1[tid][1004] = make_float4(0.f, 0.f, 0.f, 0.f);
  }
  __syncthreads();
  // ---- Phase B: conv2 over in-LDS h1 -> stats2 + pooled raw y2p ----
  float y2[8][4];
#pragma unroll
  for (int o = 0; o < 8; o++)
#pragma unroll
    for (int r = 0; r < 4; r++) y2[o][r] = 0.f;
  if (tid < 250) {                                  // 4*250 = 1000 exactly
#pragma unroll 1
    for (int c = 0; c < 4; c++) {
      float xr[12];
      const float4* xp = (const float4*)&s_h1[c][4 * tid];
#pragma unroll
      for (int v = 0; v < 3; v++) {
        float4 t = xp[v];
        xr[4 * v + 0] = t.x; xr[4 * v + 1] = t.y;
        xr[4 * v + 2] = t.z; xr[4 * v + 3] = t.w;
      }
#pragma unroll
      for (int k = 0; k < 7; k++) {
        // uniform (c,k compile-time/loop-uniform) -> s_load_dwordx4
        float4 w0 = *(const float4*)&w2t[(c * 7 + k) * 8];
        float4 w1v = *(const float4*)&w2t[(c * 7 + k) * 8 + 4];
#pragma unroll
        for (int r = 0; r < 4; r++) {
          float xv = xr[r + k + 1];
          y2[0][r] += w0.x * xv;
          y2[1][r] += w0.y * xv;
          y2[2][r] += w0.z * xv;
          y2[3][r] += w0.w * xv;
          y2[4][r] += w1v.x * xv;
          y2[5][r] += w1v.y * xv;
          y2[6][r] += w1v.z * xv;
          y2[7][r] += w1v.w * xv;
        }
      }
    }
    long yb = ((long)n * BSZ + b) * 4000 + 2 * tid;
#pragma unroll
    for (int o = 0; o < 8; o++) {
      float2 v;
      v.x = fmaxf(y2[o][0], y2[o][1]);
      v.y = fmaxf(y2[o][2], y2[o][3]);
      *(float2*)&y2p[yb + o * 500] = v;
    }
  }
  int lane = tid & 63, wv = tid >> 6;
#pragma unroll
  for (int o = 0; o < 8; o++) {
    float s = y2[o][0] + y2[o][1] + y2[o][2] + y2[o][3];
    float q = y2[o][0] * y2[o][0] + y2[o][1] * y2[o][1] +
              y2[o][2] * y2[o][2] + y2[o][3] * y2[o][3];
#pragma unroll
    for (int off = 32; off > 0; off >>= 1) {
      s += __shfl_down(s, off, 64);
      q += __shfl_down(q, off, 64);
    }
    if (lane == 0) { s_red[0][wv][o] = s; s_red[1][wv][o] = q; }
  }
  __syncthreads();
  if (tid < 8) {
    float s = 0.f, q = 0.f;
#pragma unroll
    for (int g = 0; g < 4; g++) { s += s_red[0][g][tid]; q += s_red[1][g][tid]; }
    long slot = (long)n * BSZ + b;
    p2[slot * 16 + tid] = s;
    p2[slot * 16 + 8 + tid] = q;
  }
}

// ---------------------------------------------------------------------------
// F2: read y2p, BN2+ReLU -> h2 in LDS, conv3 (channel-split) -> pooled raw
// conv3 (y3p) + stats3 partials. Weights via SGPR (readfirstlane makes og
// provably wave-uniform -> s_load). grid: (1, B, N), block 256.
// ---------------------------------------------------------------------------
__global__ __launch_bounds__(256) void fused2(
    const float* __restrict__ y2p,    // [n][b][8][500]
    const float* __restrict__ scs2,
    const float* __restrict__ w3t,    // [c][k][o] transposed conv3 weights
    float* __restrict__ y3p,          // [n][b][16][250] pooled raw conv3
    float* __restrict__ p3) {         // [(n*256+b)*32]
  __shared__ alignas(16) float s_h2[8][512];    // s_h2[c][j+4] = h2row[c][j]
  __shared__ float s_sc[8], s_sh[8];
  __shared__ float s_red[2][4][8];
  int tid = threadIdx.x, n = blockIdx.z, b = blockIdx.y;
  if (tid < 8) { s_sc[tid] = scs2[n * 64 + tid]; s_sh[tid] = scs2[n * 64 + 32 + tid]; }
  __syncthreads();
  // stage + BN2 + ReLU -> s_h2 (b128 aligned writes, conflict-free)
  const float* yb2 = y2p + ((long)n * BSZ + b) * 4000;
  for (int i = tid; i < 1000; i += 256) {
    int ch = i / 125, j4 = i % 125;
    float4 v = *(const float4*)&yb2[ch * 500 + 4 * j4];
    float sc = s_sc[ch], sh = s_sh[ch];
    v.x = fmaxf(v.x * sc + sh, 0.f);
    v.y = fmaxf(v.y * sc + sh, 0.f);
    v.z = fmaxf(v.z * sc + sh, 0.f);
    v.w = fmaxf(v.w * sc + sh, 0.f);
    *(float4*)&s_h2[ch][4 * j4 + 4] = v;
  }
  if (tid < 8) {
    *(float4*)&s_h2[tid][0] = make_float4(0.f, 0.f, 0.f, 0.f);
    *(float4*)&s_h2[tid][504] = make_float4(0.f, 0.f, 0.f, 0.f);
  }
  __syncthreads();
  // conv3 channel-split over in-LDS h2; weights via uniform s_load
  int og = __builtin_amdgcn_readfirstlane(tid >> 7);  // wave-uniform
  int pt = tid & 127;
  bool valid = pt < 125;                            // 4*125 = 500 exactly
  float y3[8][4];
#pragma unroll
  for (int o = 0; o < 8; o++)
#pragma unroll
    for (int r = 0; r < 4; r++) y3[o][r] = 0.f;
  if (valid) {
#pragma unroll 1
    for (int c = 0; c < 8; c++) {
      float xr[12];
      const float4* xp = (const float4*)&s_h2[c][4 * pt];
#pragma unroll
      for (int v = 0; v < 3; v++) {
        float4 t = xp[v];
        xr[4 * v + 0] = t.x; xr[4 * v + 1] = t.y;
        xr[4 * v + 2] = t.z; xr[4 * v + 3] = t.w;
      }
#pragma unroll
      for (int k = 0; k < 7; k++) {
        float4 w0 = *(const float4*)&w3t[(c * 7 + k) * 16 + og * 8];
        float4 w1v = *(const float4*)&w3t[(c * 7 + k) * 16 + og * 8 + 4];
#pragma unroll
        for (int r = 0; r < 4; r++) {
          float xv = xr[r + k + 1];
          y3[0][r] += w0.x * xv;
          y3[1][r] += w0.y * xv;
          y3[2][r] += w0.z * xv;
          y3[3][r] += w0.w * xv;
          y3[4][r] += w1v.x * xv;
          y3[5][r] += w1v.y * xv;
          y3[6][r] += w1v.z * xv;
          y3[7][r] += w1v.w * xv;
        }
      }
    }
    long yb = (((long)n * BSZ + b) * 16 + og * 8) * 250 + 2 * pt;
#pragma unroll
    for (int o = 0; o < 8; o++) {
      float2 v;
      v.x = fmaxf(y3[o][0], y3[o][1]);
      v.y = fmaxf(y3[o][2], y3[o][3]);
      *(float2*)&y3p[yb + o * 250] = v;
    }
  }
  int lane = tid & 63, wv = tid >> 6;
#pragma unroll
  for (int o = 0; o < 8; o++) {
    float s = y3[o][0] + y3[o][1] + y3[o][2] + y3[o][3];
    float q = y3[o][0] * y3[o][0] + y3[o][1] * y3[o][1] +
              y3[o][2] * y3[o][2] + y3[o][3] * y3[o][3];
#pragma unroll
    for (int off = 32; off > 0; off >>= 1) {
      s += __shfl_down(s, off, 64);
      q += __shfl_down(q, off, 64);
    }
    if (lane == 0) { s_red[0][wv][o] = s; s_red[1][wv][o] = q; }
  }
  __syncthreads();
  if (tid < 16) {
    int og2 = tid >> 3, o = tid & 7;
    float s = s_red[0][2 * og2][o] + s_red[0][2 * og2 + 1][o];
    float q = s_red[1][2 * og2][o] + s_red[1][2 * og2 + 1][o];
    long slot = (long)n * BSZ + b;
    p3[slot * 32 + tid] = s;
    p3[slot * 32 + 16 + tid] = q;
  }
}

// ---------------------------------------------------------------------------
// F3: BN3 + ReLU + avg over pooled raw conv3 -> feat[b][n][16].
// grid: (1, B, N), block 256 (16 chans x 16 threads).
// ---------------------------------------------------------------------------
__global__ __launch_bounds__(256) void feat_apply(
    const float* __restrict__ y3p,
    const float* __restrict__ scs3,
    float* __restrict__ feat) {
  int tid = threadIdx.x, n = blockIdx.z, b = blockIdx.y;
  int ch = tid >> 4, s = tid & 15;
  const float* yb = y3p + (((long)n * BSZ + b) * 16 + ch) * 250;
  float sc = scs3[n * 64 + ch], sh = scs3[n * 64 + 32 + ch];
  float acc = 0.f;
  for (int j = s; j < 125; j += 16) {
    float2 v = *(const float2*)&yb[2 * j];
    acc += fmaxf(v.x * sc + sh, 0.f) + fmaxf(v.y * sc + sh, 0.f);
  }
#pragma unroll
  for (int off = 8; off > 0; off >>= 1) acc += __shfl_down(acc, off, 16);
  if (s == 0) feat[((long)b * NND + n) * 16 + ch] = acc * (1.0f / 250.f);
}

// ---------------------------------------------------------------------------
// Graph tail: adjacency (top-4 incl self) + 3 GCN layers + node-mean + MLP
// grid: (B), block: 256.
// ---------------------------------------------------------------------------
__global__ __launch_bounds__(256) void graph_head(
    const float* __restrict__ feat,
    const float* __restrict__ gw1, const float* __restrict__ gb1,
    const float* __restrict__ gw2, const float* __restrict__ gb2,
    const float* __restrict__ gw3, const float* __restrict__ gb3,
    const float* __restrict__ fw1, const float* __restrict__ fb1,
    const float* __restrict__ fw2, const float* __restrict__ fb2,
    float* __restrict__ out) {
  int b = blockIdx.x, tid = threadIdx.x;
  __shared__ float s_feat[NND][16];
  __shared__ float s_sq[NND];
  __shared__ float s_dist[NND][NND];
  __shared__ float s_adj[NND][NND];
  __shared__ float s_x[NND][128];
  __shared__ float s_t[NND][128];
  __shared__ float s_pool[128];
  __shared__ float s_h[64];
  for (int i = tid; i < NND * 16; i += 256) s_feat[i >> 4][i & 15] = feat[b * NND * 16 + i];
  __syncthreads();
  if (tid < NND) {
    float s = 0.f;
    for (int c = 0; c < 16; c++) s += s_feat[tid][c] * s_feat[tid][c];
    s_sq[tid] = s;
  }
  __syncthreads();
  for (int i = tid; i < NND * NND; i += 256) {
    int nn = i / NND, m = i % NND;
    float d = 0.f;
    for (int c = 0; c < 16; c++) d += s_feat[nn][c] * s_feat[m][c];
    s_dist[nn][m] = s_sq[nn] + s_sq[m] - 2.f * d;  // diagonal exactly 0
    s_adj[nn][m] = 0.f;
  }
  __syncthreads();
  if (tid < NND) {  // top-4 smallest, ties -> earliest index (matches top_k)
    unsigned used = 0;
    for (int j = 0; j < 4; j++) {
      float best = 3.4e38f; int bi = 0;
      for (int m = 0; m < NND; m++)
        if (!((used >> m) & 1u) && s_dist[tid][m] < best) { best = s_dist[tid][m]; bi = m; }
      used |= 1u << bi;
      s_adj[tid][bi] = 0.25f;
    }
  }
  __syncthreads();
  for (int i = tid; i < NND * 32; i += 256) {
    int nn = i / 32, f = i % 32;
    float a = 0.f;
    for (int c = 0; c < 16; c++) a += s_feat[nn][c] * gw1[c * 32 + f];
    s_t[nn][f] = a;
  }
  __syncthreads();
  for (int i = tid; i < NND * 32; i += 256) {
    int nn = i / 32, f = i % 32;
    float a = gb1[f];
    for (int m = 0; m < NND; m++) a += s_adj[nn][m] * s_t[m][f];
    s_x[nn][f] = fmaxf(a, 0.f);
  }
  __syncthreads();
  for (int i = tid; i < NND * 64; i += 256) {
    int nn = i / 64, f = i % 64;
    float a = 0.f;
    for (int c = 0; c < 32; c++) a += s_x[nn][c] * gw2[c * 64 + f];
    s_t[nn][f] = a;
  }
  __syncthreads();
  for (int i = tid; i < NND * 64; i += 256) {
    int nn = i / 64, f = i % 64;
    float a = gb2[f];
    for (int m = 0; m < NND; m++) a += s_adj[nn][m] * s_t[m][f];
    s_x[nn][f] = fmaxf(a, 0.f);
  }
  __syncthreads();
  for (int i = tid; i < NND * 128; i += 256) {
    int nn = i / 128, f = i % 128;
    float a = 0.f;
    for (int c = 0; c < 64; c++) a += s_x[nn][c] * gw3[c * 128 + f];
    s_t[nn][f] = a;
  }
  __syncthreads();
  for (int i = tid; i < NND * 128; i += 256) {
    int nn = i / 128, f = i % 128;
    float a = gb3[f];
    for (int m = 0; m < NND; m++) a += s_adj[nn][m] * s_t[m][f];
    s_x[nn][f] = fmaxf(a, 0.f);
  }
  __syncthreads();
  if (tid < 128) {
    float a = 0.f;
    for (int m = 0; m < NND; m++) a += s_x[m][tid];
    s_pool[tid] = a * (1.0f / (float)NND);
  }
  __syncthreads();
  if (tid < 64) {
    float a = fb1[tid];
    for (int c = 0; c < 128; c++) a += s_pool[c] * fw1[c * 64 + tid];
    s_h[tid] = a;
  }
  __syncthreads();
  if (tid < 4) {
    float a = fb2[tid];
    for (int c = 0; c < 64; c++) a += s_h[c] * fw2[c * 4 + tid];
    out[b * 4 + tid] = a;
  }
}

extern "C" void kernel_launch(void* const* d_in, const int* in_sizes, int n_in,
                              void* d_out, int out_size, void* d_ws, size_t ws_size,
                              hipStream_t stream) {
  (void)in_sizes; (void)n_in; (void)out_size; (void)ws_size;
  const float* x   = (const float*)d_in[0];
  const float* w1  = (const float*)d_in[1];
  const float* g1  = (const float*)d_in[2];
  const float* b1  = (const float*)d_in[3];
  const float* w2  = (const float*)d_in[4];
  const float* g2  = (const float*)d_in[5];
  const float* b2  = (const float*)d_in[6];
  const float* w3  = (const float*)d_in[7];
  const float* g3  = (const float*)d_in[8];
  const float* b3  = (const float*)d_in[9];
  const float* gw1 = (const float*)d_in[10];
  const float* gb1 = (const float*)d_in[11];
  const float* gw2 = (const float*)d_in[12];
  const float* gb2 = (const float*)d_in[13];
  const float* gw3 = (const float*)d_in[14];
  const float* gb3 = (const float*)d_in[15];
  const float* fw1 = (const float*)d_in[16];
  const float* fb1 = (const float*)d_in[17];
  const float* fw2 = (const float*)d_in[18];
  const float* fb2 = (const float*)d_in[19];

  float* ws = (float*)d_ws;
  const long Y2 = (long)NND * BSZ * 8 * 500;    // 22,528,000 floats
  const long Y3 = (long)NND * BSZ * 16 * 250;   // 22,528,000 floats
  float* y2p  = ws;
  float* y3p  = y2p + Y2;
  float* feat = y3p + Y3;                       // B*N*16 = 90,112
  float* scs1 = feat + (long)BSZ * NND * 16;
  float* scs2 = scs1 + NND * 64;
  float* scs3 = scs2 + NND * 64;
  float* p1   = scs3 + NND * 64;                // 22*512 slots * 8
  float* p2   = p1 + (long)NND * 512 * 8;       // 22*256 slots * 16
  float* p3   = p2 + (long)NND * 256 * 16;      // 22*256 slots * 32
  float* w2t  = p3 + (long)NND * 256 * 32;      // 224
  float* w3t  = w2t + 224;                      // 896
  // total ws ~= 182 MB (same budget as prior passing rounds)

  // weight pre-transpose (one tiny block)
  prep_weights<<<dim3(1), dim3(256), 0, stream>>>(w2, w3, w2t, w3t);
  // stats1 over x
  conv_statsR<1, 4, 2000, 256, 2, 4><<<dim3(2, BSZ, NND), dim3(256), 0, stream>>>(
      x, 2000, (long)NND * 2000, 0, w1, p1);
  stats_reduce<4, 512, 2000><<<dim3(NND), dim3(256), 0, stream>>>(p1, g1, b1, scs1);
  // conv1-apply + conv2 (pooled raw out) + stats2 (fused; h1 stays in LDS)
  fused1<<<dim3(1, BSZ, NND), dim3(256), 0, stream>>>(x, w1, scs1, w2t, y2p, p2);
  stats_reduce<8, 256, 1000><<<dim3(NND), dim3(256), 0, stream>>>(p2, g2, b2, scs2);
  // BN2-apply + conv3 (pooled raw out) + stats3 (fused; no conv2 recompute)
  fused2<<<dim3(1, BSZ, NND), dim3(256), 0, stream>>>(y2p, scs2, w3t, y3p, p3);
  stats_reduce<16, 256, 500><<<dim3(NND), dim3(256), 0, stream>>>(p3, g3, b3, scs3);
  // BN3 + ReLU + avg -> feat
  feat_apply<<<dim3(1, BSZ, NND), dim3(256), 0, stream>>>(y3p, scs3, feat);
  // graph tail
  graph_head<<<dim3(BSZ), dim3(256), 0, stream>>>(
      feat, gw1, gb1, gw2, gb2, gw3, gb3, fw1, fb1, fw2, fb2, (float*)d_out);
}